// Round 1
// baseline (497.029 us; speedup 1.0000x reference)
//
#include <hip/hip_runtime.h>
#include <hip/hip_bf16.h>
#include <math.h>

// FPLayer: 3-NN inverse-distance interpolation + concat + 2x (Conv1d(k=1) -> BN(train) -> ReLU)
// B=8 N1=8192 N2=2048 C1=128 C2=256 MLP=[256,128]

#define NB 8
#define NP1 8192
#define NP2 2048
#define C1 128
#define C2 256
#define H0 256
#define H1 128
#define MT (NB * NP1)   // 65536 rows
#define TM (MT / 64)    // 1024 row-tiles
#define BN_EPS 1e-5f
#define LPAD 68

// ---------------- KNN: top-3 neighbors + inverse-distance weights ----------------
__global__ __launch_bounds__(256) void knn_kernel(
    const float* __restrict__ xyz1, const float* __restrict__ xyz2,
    int* __restrict__ knn_idx, float* __restrict__ knn_w)
{
  __shared__ __align__(16) float4 s2[NP2];   // {x, y, z, |p|^2}  32 KB
  const int b = blockIdx.y;
  const float* p2 = xyz2 + (size_t)b * NP2 * 3;
  for (int j = threadIdx.x; j < NP2; j += 256) {
    float x = p2[j * 3 + 0], y = p2[j * 3 + 1], z = p2[j * 3 + 2];
    float sq = __fadd_rn(__fadd_rn(__fmul_rn(x, x), __fmul_rn(y, y)), __fmul_rn(z, z));
    s2[j] = make_float4(x, y, z, sq);
  }
  __syncthreads();
  const int n = blockIdx.x * 256 + threadIdx.x;
  const float* p1 = xyz1 + ((size_t)b * NP1 + n) * 3;
  const float ax = p1[0], ay = p1[1], az = p1[2];
  const float sq1 = __fadd_rn(__fadd_rn(__fmul_rn(ax, ax), __fmul_rn(ay, ay)), __fmul_rn(az, az));
  // mirror reference rounding: d2 = (sq1 + sq2) - 2*dot, products individually rounded (no FMA)
  float b0v = 3.4e38f, b1v = 3.4e38f, b2v = 3.4e38f;
  int i0 = 0, i1 = 0, i2 = 0;
  for (int j = 0; j < NP2; ++j) {
    float4 p = s2[j];
    float dot = __fadd_rn(__fadd_rn(__fmul_rn(ax, p.x), __fmul_rn(ay, p.y)), __fmul_rn(az, p.z));
    float d2 = __fsub_rn(__fadd_rn(sq1, p.w), __fmul_rn(2.0f, dot));
    d2 = fmaxf(d2, 1e-12f);   // clamp BEFORE compare: matches sqrt(max(...)) ordering incl. ties
    if (d2 < b2v) {
      if (d2 < b1v) {
        b2v = b1v; i2 = i1;
        if (d2 < b0v) { b1v = b0v; i1 = i0; b0v = d2; i0 = j; }
        else          { b1v = d2; i1 = j; }
      } else { b2v = d2; i2 = j; }
    }
  }
  const float s0 = sqrtf(b0v), s1 = sqrtf(b1v), s2d = sqrtf(b2v);
  const float r0 = 1.0f / (s0 + 1e-8f), r1 = 1.0f / (s1 + 1e-8f), r2 = 1.0f / (s2d + 1e-8f);
  const float rs = __fadd_rn(__fadd_rn(r0, r1), r2);
  const size_t o = ((size_t)b * NP1 + n) * 3;
  knn_idx[o] = i0; knn_idx[o + 1] = i1; knn_idx[o + 2] = i2;
  knn_w[o] = r0 / rs; knn_w[o + 1] = r1 / rs; knn_w[o + 2] = r2 / rs;
}

// ---------------- Interpolate: gather 3 neighbor features, weighted sum ----------------
__global__ __launch_bounds__(256) void interp_kernel(
    const float* __restrict__ feat2, const int* __restrict__ knn_idx,
    const float* __restrict__ knn_w, float* __restrict__ interp)
{
  const int m  = blockIdx.x * 4 + (threadIdx.x >> 6);  // 4 points per block
  const int c4 = threadIdx.x & 63;                     // float4 channel slot (256/4)
  const int b  = m >> 13;                              // m / NP1
  const size_t o = (size_t)m * 3;
  const int i0 = knn_idx[o], i1 = knn_idx[o + 1], i2 = knn_idx[o + 2];
  const float w0 = knn_w[o], w1 = knn_w[o + 1], w2 = knn_w[o + 2];
  const float4* f2 = (const float4*)feat2;
  const size_t base = (size_t)b * NP2 * (C2 / 4);
  float4 f0 = f2[base + (size_t)i0 * (C2 / 4) + c4];
  float4 f1 = f2[base + (size_t)i1 * (C2 / 4) + c4];
  float4 fv = f2[base + (size_t)i2 * (C2 / 4) + c4];
  float4 r;
  r.x = w0 * f0.x + w1 * f1.x + w2 * fv.x;
  r.y = w0 * f0.y + w1 * f1.y + w2 * fv.y;
  r.z = w0 * f0.z + w1 * f1.z + w2 * fv.z;
  r.w = w0 * f0.w + w1 * f1.w + w2 * fv.w;
  ((float4*)interp)[(size_t)m * (C2 / 4) + c4] = r;
}

// ---------------- GEMM0: y0 = [feat1|interp] @ W0^T + b0, + column partial sums ----------------
__global__ __launch_bounds__(256) void gemm0_kernel(
    const float* __restrict__ feat1, const float* __restrict__ interp,
    const float* __restrict__ W0, const float* __restrict__ b0,
    float* __restrict__ y0, float2* __restrict__ part0)
{
  __shared__ __align__(16) float As[32][LPAD];
  __shared__ __align__(16) float Bs[32][LPAD];
  __shared__ float red[16][64];
  const int tm = blockIdx.x, tn = blockIdx.y;
  const int tid = threadIdx.x;
  const int tx = tid & 15, ty = tid >> 4;
  const int lr = tid >> 3;           // 0..31 (row within half-tile)
  const int lk = (tid & 7) << 2;     // k offset 0..28
  const int row0 = tm * 64, col0 = tn * 64;
  float acc[4][4] = {};
  for (int k0 = 0; k0 < (C1 + C2); k0 += 32) {
    #pragma unroll
    for (int h = 0; h < 2; ++h) {
      const int r = lr + h * 32;
      float4 a;
      if (k0 < C1) a = *(const float4*)(feat1  + (size_t)(row0 + r) * C1 + k0 + lk);
      else         a = *(const float4*)(interp + (size_t)(row0 + r) * C2 + (k0 - C1) + lk);
      const float4 w = *(const float4*)(W0 + (size_t)(col0 + r) * (C1 + C2) + k0 + lk);
      As[lk + 0][r] = a.x; As[lk + 1][r] = a.y; As[lk + 2][r] = a.z; As[lk + 3][r] = a.w;
      Bs[lk + 0][r] = w.x; Bs[lk + 1][r] = w.y; Bs[lk + 2][r] = w.z; Bs[lk + 3][r] = w.w;
    }
    __syncthreads();
    #pragma unroll
    for (int kk = 0; kk < 32; ++kk) {
      const float4 av = *(const float4*)&As[kk][ty * 4];
      const float4 bv = *(const float4*)&Bs[kk][tx * 4];
      const float aa[4] = {av.x, av.y, av.z, av.w};
      const float bb[4] = {bv.x, bv.y, bv.z, bv.w};
      #pragma unroll
      for (int i = 0; i < 4; ++i)
        #pragma unroll
        for (int j = 0; j < 4; ++j) acc[i][j] = fmaf(aa[i], bb[j], acc[i][j]);
    }
    __syncthreads();
  }
  const float4 bias = *(const float4*)(b0 + col0 + tx * 4);
  const float bb4[4] = {bias.x, bias.y, bias.z, bias.w};
  float colS[4] = {0, 0, 0, 0}, colQ[4] = {0, 0, 0, 0};
  #pragma unroll
  for (int i = 0; i < 4; ++i) {
    float v[4];
    #pragma unroll
    for (int j = 0; j < 4; ++j) {
      v[j] = acc[i][j] + bb4[j];
      colS[j] += v[j];
      colQ[j] = fmaf(v[j], v[j], colQ[j]);
    }
    float4 ov = {v[0], v[1], v[2], v[3]};
    *(float4*)(y0 + (size_t)(row0 + ty * 4 + i) * H0 + col0 + tx * 4) = ov;
  }
  #pragma unroll
  for (int j = 0; j < 4; ++j) red[ty][tx * 4 + j] = colS[j];
  __syncthreads();
  float sum64 = 0.f;
  if (tid < 64) {
    #pragma unroll
    for (int t = 0; t < 16; ++t) sum64 += red[t][tid];
  }
  __syncthreads();
  #pragma unroll
  for (int j = 0; j < 4; ++j) red[ty][tx * 4 + j] = colQ[j];
  __syncthreads();
  if (tid < 64) {
    float q64 = 0.f;
    #pragma unroll
    for (int t = 0; t < 16; ++t) q64 += red[t][tid];
    part0[(size_t)(col0 + tid) * TM + tm] = make_float2(sum64, q64);
  }
}

// ---------------- BN finalize: mean/var -> scale/shift ----------------
__global__ __launch_bounds__(256) void bnfin_kernel(
    const float2* __restrict__ part, const float* __restrict__ gamma,
    const float* __restrict__ beta, float* __restrict__ sc, float* __restrict__ sh)
{
  __shared__ float2 red[256];
  const int ch = blockIdx.x, tid = threadIdx.x;
  float s = 0.f, q = 0.f;
  for (int t = tid; t < TM; t += 256) {
    float2 p = part[(size_t)ch * TM + t];
    s += p.x; q += p.y;
  }
  red[tid] = make_float2(s, q);
  __syncthreads();
  for (int off = 128; off > 0; off >>= 1) {
    if (tid < off) { float2 o = red[tid + off]; red[tid].x += o.x; red[tid].y += o.y; }
    __syncthreads();
  }
  if (tid == 0) {
    const float mean = red[0].x / (float)MT;
    const float var  = red[0].y / (float)MT - mean * mean;
    const float scale = gamma[ch] / sqrtf(var + BN_EPS);
    sc[ch] = scale;
    sh[ch] = beta[ch] - mean * scale;
  }
}

// ---------------- GEMM1: y1 = relu(bn0(y0)) @ W1^T + b1, + column partial sums ----------------
__global__ __launch_bounds__(256) void gemm1_kernel(
    const float* __restrict__ y0, const float* __restrict__ sc0, const float* __restrict__ sh0,
    const float* __restrict__ W1, const float* __restrict__ b1,
    float* __restrict__ y1, float2* __restrict__ part1)
{
  __shared__ __align__(16) float As[32][LPAD];
  __shared__ __align__(16) float Bs[32][LPAD];
  __shared__ float red[16][64];
  const int tm = blockIdx.x, tn = blockIdx.y;
  const int tid = threadIdx.x;
  const int tx = tid & 15, ty = tid >> 4;
  const int lr = tid >> 3;
  const int lk = (tid & 7) << 2;
  const int row0 = tm * 64, col0 = tn * 64;
  float acc[4][4] = {};
  for (int k0 = 0; k0 < H0; k0 += 32) {
    const float4 s4 = *(const float4*)(sc0 + k0 + lk);
    const float4 h4 = *(const float4*)(sh0 + k0 + lk);
    #pragma unroll
    for (int h = 0; h < 2; ++h) {
      const int r = lr + h * 32;
      float4 a = *(const float4*)(y0 + (size_t)(row0 + r) * H0 + k0 + lk);
      a.x = fmaxf(fmaf(a.x, s4.x, h4.x), 0.f);
      a.y = fmaxf(fmaf(a.y, s4.y, h4.y), 0.f);
      a.z = fmaxf(fmaf(a.z, s4.z, h4.z), 0.f);
      a.w = fmaxf(fmaf(a.w, s4.w, h4.w), 0.f);
      const float4 w = *(const float4*)(W1 + (size_t)(col0 + r) * H0 + k0 + lk);
      As[lk + 0][r] = a.x; As[lk + 1][r] = a.y; As[lk + 2][r] = a.z; As[lk + 3][r] = a.w;
      Bs[lk + 0][r] = w.x; Bs[lk + 1][r] = w.y; Bs[lk + 2][r] = w.z; Bs[lk + 3][r] = w.w;
    }
    __syncthreads();
    #pragma unroll
    for (int kk = 0; kk < 32; ++kk) {
      const float4 av = *(const float4*)&As[kk][ty * 4];
      const float4 bv = *(const float4*)&Bs[kk][tx * 4];
      const float aa[4] = {av.x, av.y, av.z, av.w};
      const float bb[4] = {bv.x, bv.y, bv.z, bv.w};
      #pragma unroll
      for (int i = 0; i < 4; ++i)
        #pragma unroll
        for (int j = 0; j < 4; ++j) acc[i][j] = fmaf(aa[i], bb[j], acc[i][j]);
    }
    __syncthreads();
  }
  const float4 bias = *(const float4*)(b1 + col0 + tx * 4);
  const float bb4[4] = {bias.x, bias.y, bias.z, bias.w};
  float colS[4] = {0, 0, 0, 0}, colQ[4] = {0, 0, 0, 0};
  #pragma unroll
  for (int i = 0; i < 4; ++i) {
    float v[4];
    #pragma unroll
    for (int j = 0; j < 4; ++j) {
      v[j] = acc[i][j] + bb4[j];
      colS[j] += v[j];
      colQ[j] = fmaf(v[j], v[j], colQ[j]);
    }
    float4 ov = {v[0], v[1], v[2], v[3]};
    *(float4*)(y1 + (size_t)(row0 + ty * 4 + i) * H1 + col0 + tx * 4) = ov;
  }
  #pragma unroll
  for (int j = 0; j < 4; ++j) red[ty][tx * 4 + j] = colS[j];
  __syncthreads();
  float sum64 = 0.f;
  if (tid < 64) {
    #pragma unroll
    for (int t = 0; t < 16; ++t) sum64 += red[t][tid];
  }
  __syncthreads();
  #pragma unroll
  for (int j = 0; j < 4; ++j) red[ty][tx * 4 + j] = colQ[j];
  __syncthreads();
  if (tid < 64) {
    float q64 = 0.f;
    #pragma unroll
    for (int t = 0; t < 16; ++t) q64 += red[t][tid];
    part1[(size_t)(col0 + tid) * TM + tm] = make_float2(sum64, q64);
  }
}

// ---------------- Final BN1 + ReLU ----------------
__global__ __launch_bounds__(256) void bnrelu_out_kernel(
    const float* __restrict__ y1, const float* __restrict__ sc1,
    const float* __restrict__ sh1, float* __restrict__ out)
{
  const size_t i = (size_t)blockIdx.x * 256 + threadIdx.x;  // float4 index
  const int c4 = (int)(i & (H1 / 4 - 1));
  float4 v = ((const float4*)y1)[i];
  const float4 s = ((const float4*)sc1)[c4];
  const float4 h = ((const float4*)sh1)[c4];
  v.x = fmaxf(fmaf(v.x, s.x, h.x), 0.f);
  v.y = fmaxf(fmaf(v.y, s.y, h.y), 0.f);
  v.z = fmaxf(fmaf(v.z, s.z, h.z), 0.f);
  v.w = fmaxf(fmaf(v.w, s.w, h.w), 0.f);
  ((float4*)out)[i] = v;
}

extern "C" void kernel_launch(void* const* d_in, const int* in_sizes, int n_in,
                              void* d_out, int out_size, void* d_ws, size_t ws_size,
                              hipStream_t stream)
{
  const float* xyz1  = (const float*)d_in[0];
  const float* xyz2  = (const float*)d_in[1];
  const float* feat1 = (const float*)d_in[2];
  const float* feat2 = (const float*)d_in[3];
  const float* W0  = (const float*)d_in[4];
  const float* b0  = (const float*)d_in[5];
  const float* g0  = (const float*)d_in[6];
  const float* be0 = (const float*)d_in[7];
  const float* W1  = (const float*)d_in[8];
  const float* b1  = (const float*)d_in[9];
  const float* g1  = (const float*)d_in[10];
  const float* be1 = (const float*)d_in[11];
  float* out = (float*)d_out;

  // workspace layout (~139 MB)
  char* ws = (char*)d_ws;
  size_t off = 0;
  float* interp = (float*)(ws + off); off += (size_t)MT * C2 * 4;   // 67.1 MB (reused as y1)
  float* y0     = (float*)(ws + off); off += (size_t)MT * H0 * 4;   // 67.1 MB
  int*   kidx   = (int*)(ws + off);   off += (size_t)MT * 3 * 4;
  float* kw     = (float*)(ws + off); off += (size_t)MT * 3 * 4;
  float2* part0 = (float2*)(ws + off); off += (size_t)H0 * TM * 8;
  float2* part1 = (float2*)(ws + off); off += (size_t)H1 * TM * 8;
  float* sc0 = (float*)(ws + off); off += H0 * 4;
  float* sh0 = (float*)(ws + off); off += H0 * 4;
  float* sc1 = (float*)(ws + off); off += H1 * 4;
  float* sh1 = (float*)(ws + off); off += H1 * 4;
  float* y1 = interp;  // interp is dead after gemm0 -> alias

  knn_kernel<<<dim3(NP1 / 256, NB), 256, 0, stream>>>(xyz1, xyz2, kidx, kw);
  interp_kernel<<<dim3(MT / 4), 256, 0, stream>>>(feat2, kidx, kw, interp);
  gemm0_kernel<<<dim3(TM, H0 / 64), 256, 0, stream>>>(feat1, interp, W0, b0, y0, part0);
  bnfin_kernel<<<dim3(H0), 256, 0, stream>>>(part0, g0, be0, sc0, sh0);
  gemm1_kernel<<<dim3(TM, H1 / 64), 256, 0, stream>>>(y0, sc0, sh0, W1, b1, y1, part1);
  bnfin_kernel<<<dim3(H1), 256, 0, stream>>>(part1, g1, be1, sc1, sh1);
  bnrelu_out_kernel<<<dim3(MT * H1 / 4 / 256), 256, 0, stream>>>(y1, sc1, sh1, out);
}

// Round 2
// 360.168 us; speedup vs baseline: 1.3800x; 1.3800x over previous
//
#include <hip/hip_runtime.h>
#include <hip/hip_bf16.h>
#include <math.h>

// FPLayer: 3-NN inverse-distance interpolation + concat + 2x (Conv1d(k=1) -> BN(train) -> ReLU)
// B=8 N1=8192 N2=2048 C1=128 C2=256 MLP=[256,128]

#define NB 8
#define NP1 8192
#define NP2 2048
#define C1 128
#define C2 256
#define H0 256
#define H1 128
#define MT (NB * NP1)   // 65536 rows
#define TM (MT / 64)    // 1024 row-tiles
#define BN_EPS 1e-5f
#define LPAD 68
#define NCHUNK 8
#define CHSZ (NP2 / NCHUNK)   // 256

// ---------------- KNN phase 1: per-chunk top-3 candidates ----------------
// grid (NP1/256, NB, NCHUNK). Each block: one 256-query group x one 256-ref chunk.
__global__ __launch_bounds__(256) void knn_chunk_kernel(
    const float* __restrict__ xyz1, const float* __restrict__ xyz2,
    float2* __restrict__ cand)
{
  __shared__ __align__(16) float4 s2[CHSZ];   // {x, y, z, |p|^2}  4 KB
  const int b = blockIdx.y, c = blockIdx.z;
  const float* p2 = xyz2 + ((size_t)b * NP2 + c * CHSZ) * 3;
  {
    const int j = threadIdx.x;   // CHSZ == blockDim
    float x = p2[j * 3 + 0], y = p2[j * 3 + 1], z = p2[j * 3 + 2];
    float sq = __fadd_rn(__fadd_rn(__fmul_rn(x, x), __fmul_rn(y, y)), __fmul_rn(z, z));
    s2[j] = make_float4(x, y, z, sq);
  }
  __syncthreads();
  const int n = blockIdx.x * 256 + threadIdx.x;
  const float* p1 = xyz1 + ((size_t)b * NP1 + n) * 3;
  const float ax = p1[0], ay = p1[1], az = p1[2];
  const float sq1 = __fadd_rn(__fadd_rn(__fmul_rn(ax, ax), __fmul_rn(ay, ay)), __fmul_rn(az, az));
  // mirror reference rounding: d2 = (sq1 + sq2) - 2*dot, products individually rounded (no FMA)
  float b0v = 3.4e38f, b1v = 3.4e38f, b2v = 3.4e38f;
  int i0 = 0, i1 = 0, i2 = 0;
  #pragma unroll 4
  for (int j = 0; j < CHSZ; ++j) {
    float4 p = s2[j];
    float dot = __fadd_rn(__fadd_rn(__fmul_rn(ax, p.x), __fmul_rn(ay, p.y)), __fmul_rn(az, p.z));
    float d2 = __fsub_rn(__fadd_rn(sq1, p.w), __fmul_rn(2.0f, dot));
    d2 = fmaxf(d2, 1e-12f);   // clamp BEFORE compare: matches sqrt(max(...)) ordering incl. ties
    if (d2 < b2v) {
      if (d2 < b1v) {
        b2v = b1v; i2 = i1;
        if (d2 < b0v) { b1v = b0v; i1 = i0; b0v = d2; i0 = j; }
        else          { b1v = d2; i1 = j; }
      } else { b2v = d2; i2 = j; }
    }
  }
  const int jb = c * CHSZ;
  const size_t o = (((size_t)b * NP1 + n) * NCHUNK + c) * 3;
  cand[o + 0] = make_float2(b0v, __int_as_float(jb + i0));
  cand[o + 1] = make_float2(b1v, __int_as_float(jb + i1));
  cand[o + 2] = make_float2(b2v, __int_as_float(jb + i2));
}

// ---------------- KNN phase 2: merge 8x3 candidates, compute weights ----------------
// Inserting candidates in chunk order (each chunk's triple ascending) with strict <
// reproduces the sequential full-scan result exactly, incl. tie -> lowest index.
__global__ __launch_bounds__(256) void knn_merge_kernel(
    const float2* __restrict__ cand, int* __restrict__ knn_idx, float* __restrict__ knn_w)
{
  const int m = blockIdx.x * 256 + threadIdx.x;   // global query id
  const float2* cc = cand + (size_t)m * (NCHUNK * 3);
  float b0v = 3.4e38f, b1v = 3.4e38f, b2v = 3.4e38f;
  int i0 = 0, i1 = 0, i2 = 0;
  #pragma unroll
  for (int t = 0; t < NCHUNK * 3; ++t) {
    const float2 p = cc[t];
    const float d2 = p.x;
    const int j = __float_as_int(p.y);
    if (d2 < b2v) {
      if (d2 < b1v) {
        b2v = b1v; i2 = i1;
        if (d2 < b0v) { b1v = b0v; i1 = i0; b0v = d2; i0 = j; }
        else          { b1v = d2; i1 = j; }
      } else { b2v = d2; i2 = j; }
    }
  }
  const float s0 = sqrtf(b0v), s1 = sqrtf(b1v), s2d = sqrtf(b2v);
  const float r0 = 1.0f / (s0 + 1e-8f), r1 = 1.0f / (s1 + 1e-8f), r2 = 1.0f / (s2d + 1e-8f);
  const float rs = __fadd_rn(__fadd_rn(r0, r1), r2);
  const size_t o = (size_t)m * 3;
  knn_idx[o] = i0; knn_idx[o + 1] = i1; knn_idx[o + 2] = i2;
  knn_w[o] = r0 / rs; knn_w[o + 1] = r1 / rs; knn_w[o + 2] = r2 / rs;
}

// ---------------- Interpolate: gather 3 neighbor features, weighted sum ----------------
__global__ __launch_bounds__(256) void interp_kernel(
    const float* __restrict__ feat2, const int* __restrict__ knn_idx,
    const float* __restrict__ knn_w, float* __restrict__ interp)
{
  const int m  = blockIdx.x * 4 + (threadIdx.x >> 6);  // 4 points per block
  const int c4 = threadIdx.x & 63;                     // float4 channel slot (256/4)
  const int b  = m >> 13;                              // m / NP1
  const size_t o = (size_t)m * 3;
  const int i0 = knn_idx[o], i1 = knn_idx[o + 1], i2 = knn_idx[o + 2];
  const float w0 = knn_w[o], w1 = knn_w[o + 1], w2 = knn_w[o + 2];
  const float4* f2 = (const float4*)feat2;
  const size_t base = (size_t)b * NP2 * (C2 / 4);
  float4 f0 = f2[base + (size_t)i0 * (C2 / 4) + c4];
  float4 f1 = f2[base + (size_t)i1 * (C2 / 4) + c4];
  float4 fv = f2[base + (size_t)i2 * (C2 / 4) + c4];
  float4 r;
  r.x = w0 * f0.x + w1 * f1.x + w2 * fv.x;
  r.y = w0 * f0.y + w1 * f1.y + w2 * fv.y;
  r.z = w0 * f0.z + w1 * f1.z + w2 * fv.z;
  r.w = w0 * f0.w + w1 * f1.w + w2 * fv.w;
  ((float4*)interp)[(size_t)m * (C2 / 4) + c4] = r;
}

// ---------------- GEMM0: y0 = [feat1|interp] @ W0^T + b0, + column partial sums ----------------
__global__ __launch_bounds__(256) void gemm0_kernel(
    const float* __restrict__ feat1, const float* __restrict__ interp,
    const float* __restrict__ W0, const float* __restrict__ b0,
    float* __restrict__ y0, float2* __restrict__ part0)
{
  __shared__ __align__(16) float As[32][LPAD];
  __shared__ __align__(16) float Bs[32][LPAD];
  __shared__ float red[16][64];
  const int tm = blockIdx.x, tn = blockIdx.y;
  const int tid = threadIdx.x;
  const int tx = tid & 15, ty = tid >> 4;
  const int lr = tid >> 3;           // 0..31 (row within half-tile)
  const int lk = (tid & 7) << 2;     // k offset 0..28
  const int row0 = tm * 64, col0 = tn * 64;
  float acc[4][4] = {};
  for (int k0 = 0; k0 < (C1 + C2); k0 += 32) {
    #pragma unroll
    for (int h = 0; h < 2; ++h) {
      const int r = lr + h * 32;
      float4 a;
      if (k0 < C1) a = *(const float4*)(feat1  + (size_t)(row0 + r) * C1 + k0 + lk);
      else         a = *(const float4*)(interp + (size_t)(row0 + r) * C2 + (k0 - C1) + lk);
      const float4 w = *(const float4*)(W0 + (size_t)(col0 + r) * (C1 + C2) + k0 + lk);
      As[lk + 0][r] = a.x; As[lk + 1][r] = a.y; As[lk + 2][r] = a.z; As[lk + 3][r] = a.w;
      Bs[lk + 0][r] = w.x; Bs[lk + 1][r] = w.y; Bs[lk + 2][r] = w.z; Bs[lk + 3][r] = w.w;
    }
    __syncthreads();
    #pragma unroll
    for (int kk = 0; kk < 32; ++kk) {
      const float4 av = *(const float4*)&As[kk][ty * 4];
      const float4 bv = *(const float4*)&Bs[kk][tx * 4];
      const float aa[4] = {av.x, av.y, av.z, av.w};
      const float bb[4] = {bv.x, bv.y, bv.z, bv.w};
      #pragma unroll
      for (int i = 0; i < 4; ++i)
        #pragma unroll
        for (int j = 0; j < 4; ++j) acc[i][j] = fmaf(aa[i], bb[j], acc[i][j]);
    }
    __syncthreads();
  }
  const float4 bias = *(const float4*)(b0 + col0 + tx * 4);
  const float bb4[4] = {bias.x, bias.y, bias.z, bias.w};
  float colS[4] = {0, 0, 0, 0}, colQ[4] = {0, 0, 0, 0};
  #pragma unroll
  for (int i = 0; i < 4; ++i) {
    float v[4];
    #pragma unroll
    for (int j = 0; j < 4; ++j) {
      v[j] = acc[i][j] + bb4[j];
      colS[j] += v[j];
      colQ[j] = fmaf(v[j], v[j], colQ[j]);
    }
    float4 ov = {v[0], v[1], v[2], v[3]};
    *(float4*)(y0 + (size_t)(row0 + ty * 4 + i) * H0 + col0 + tx * 4) = ov;
  }
  #pragma unroll
  for (int j = 0; j < 4; ++j) red[ty][tx * 4 + j] = colS[j];
  __syncthreads();
  float sum64 = 0.f;
  if (tid < 64) {
    #pragma unroll
    for (int t = 0; t < 16; ++t) sum64 += red[t][tid];
  }
  __syncthreads();
  #pragma unroll
  for (int j = 0; j < 4; ++j) red[ty][tx * 4 + j] = colQ[j];
  __syncthreads();
  if (tid < 64) {
    float q64 = 0.f;
    #pragma unroll
    for (int t = 0; t < 16; ++t) q64 += red[t][tid];
    part0[(size_t)(col0 + tid) * TM + tm] = make_float2(sum64, q64);
  }
}

// ---------------- BN finalize: mean/var -> scale/shift ----------------
__global__ __launch_bounds__(256) void bnfin_kernel(
    const float2* __restrict__ part, const float* __restrict__ gamma,
    const float* __restrict__ beta, float* __restrict__ sc, float* __restrict__ sh)
{
  __shared__ float2 red[256];
  const int ch = blockIdx.x, tid = threadIdx.x;
  float s = 0.f, q = 0.f;
  for (int t = tid; t < TM; t += 256) {
    float2 p = part[(size_t)ch * TM + t];
    s += p.x; q += p.y;
  }
  red[tid] = make_float2(s, q);
  __syncthreads();
  for (int off = 128; off > 0; off >>= 1) {
    if (tid < off) { float2 o = red[tid + off]; red[tid].x += o.x; red[tid].y += o.y; }
    __syncthreads();
  }
  if (tid == 0) {
    const float mean = red[0].x / (float)MT;
    const float var  = red[0].y / (float)MT - mean * mean;
    const float scale = gamma[ch] / sqrtf(var + BN_EPS);
    sc[ch] = scale;
    sh[ch] = beta[ch] - mean * scale;
  }
}

// ---------------- GEMM1: y1 = relu(bn0(y0)) @ W1^T + b1, + column partial sums ----------------
__global__ __launch_bounds__(256) void gemm1_kernel(
    const float* __restrict__ y0, const float* __restrict__ sc0, const float* __restrict__ sh0,
    const float* __restrict__ W1, const float* __restrict__ b1,
    float* __restrict__ y1, float2* __restrict__ part1)
{
  __shared__ __align__(16) float As[32][LPAD];
  __shared__ __align__(16) float Bs[32][LPAD];
  __shared__ float red[16][64];
  const int tm = blockIdx.x, tn = blockIdx.y;
  const int tid = threadIdx.x;
  const int tx = tid & 15, ty = tid >> 4;
  const int lr = tid >> 3;
  const int lk = (tid & 7) << 2;
  const int row0 = tm * 64, col0 = tn * 64;
  float acc[4][4] = {};
  for (int k0 = 0; k0 < H0; k0 += 32) {
    const float4 s4 = *(const float4*)(sc0 + k0 + lk);
    const float4 h4 = *(const float4*)(sh0 + k0 + lk);
    #pragma unroll
    for (int h = 0; h < 2; ++h) {
      const int r = lr + h * 32;
      float4 a = *(const float4*)(y0 + (size_t)(row0 + r) * H0 + k0 + lk);
      a.x = fmaxf(fmaf(a.x, s4.x, h4.x), 0.f);
      a.y = fmaxf(fmaf(a.y, s4.y, h4.y), 0.f);
      a.z = fmaxf(fmaf(a.z, s4.z, h4.z), 0.f);
      a.w = fmaxf(fmaf(a.w, s4.w, h4.w), 0.f);
      const float4 w = *(const float4*)(W1 + (size_t)(col0 + r) * H0 + k0 + lk);
      As[lk + 0][r] = a.x; As[lk + 1][r] = a.y; As[lk + 2][r] = a.z; As[lk + 3][r] = a.w;
      Bs[lk + 0][r] = w.x; Bs[lk + 1][r] = w.y; Bs[lk + 2][r] = w.z; Bs[lk + 3][r] = w.w;
    }
    __syncthreads();
    #pragma unroll
    for (int kk = 0; kk < 32; ++kk) {
      const float4 av = *(const float4*)&As[kk][ty * 4];
      const float4 bv = *(const float4*)&Bs[kk][tx * 4];
      const float aa[4] = {av.x, av.y, av.z, av.w};
      const float bb[4] = {bv.x, bv.y, bv.z, bv.w};
      #pragma unroll
      for (int i = 0; i < 4; ++i)
        #pragma unroll
        for (int j = 0; j < 4; ++j) acc[i][j] = fmaf(aa[i], bb[j], acc[i][j]);
    }
    __syncthreads();
  }
  const float4 bias = *(const float4*)(b1 + col0 + tx * 4);
  const float bb4[4] = {bias.x, bias.y, bias.z, bias.w};
  float colS[4] = {0, 0, 0, 0}, colQ[4] = {0, 0, 0, 0};
  #pragma unroll
  for (int i = 0; i < 4; ++i) {
    float v[4];
    #pragma unroll
    for (int j = 0; j < 4; ++j) {
      v[j] = acc[i][j] + bb4[j];
      colS[j] += v[j];
      colQ[j] = fmaf(v[j], v[j], colQ[j]);
    }
    float4 ov = {v[0], v[1], v[2], v[3]};
    *(float4*)(y1 + (size_t)(row0 + ty * 4 + i) * H1 + col0 + tx * 4) = ov;
  }
  #pragma unroll
  for (int j = 0; j < 4; ++j) red[ty][tx * 4 + j] = colS[j];
  __syncthreads();
  float sum64 = 0.f;
  if (tid < 64) {
    #pragma unroll
    for (int t = 0; t < 16; ++t) sum64 += red[t][tid];
  }
  __syncthreads();
  #pragma unroll
  for (int j = 0; j < 4; ++j) red[ty][tx * 4 + j] = colQ[j];
  __syncthreads();
  if (tid < 64) {
    float q64 = 0.f;
    #pragma unroll
    for (int t = 0; t < 16; ++t) q64 += red[t][tid];
    part1[(size_t)(col0 + tid) * TM + tm] = make_float2(sum64, q64);
  }
}

// ---------------- Final BN1 + ReLU ----------------
__global__ __launch_bounds__(256) void bnrelu_out_kernel(
    const float* __restrict__ y1, const float* __restrict__ sc1,
    const float* __restrict__ sh1, float* __restrict__ out)
{
  const size_t i = (size_t)blockIdx.x * 256 + threadIdx.x;  // float4 index
  const int c4 = (int)(i & (H1 / 4 - 1));
  float4 v = ((const float4*)y1)[i];
  const float4 s = ((const float4*)sc1)[c4];
  const float4 h = ((const float4*)sh1)[c4];
  v.x = fmaxf(fmaf(v.x, s.x, h.x), 0.f);
  v.y = fmaxf(fmaf(v.y, s.y, h.y), 0.f);
  v.z = fmaxf(fmaf(v.z, s.z, h.z), 0.f);
  v.w = fmaxf(fmaf(v.w, s.w, h.w), 0.f);
  ((float4*)out)[i] = v;
}

extern "C" void kernel_launch(void* const* d_in, const int* in_sizes, int n_in,
                              void* d_out, int out_size, void* d_ws, size_t ws_size,
                              hipStream_t stream)
{
  const float* xyz1  = (const float*)d_in[0];
  const float* xyz2  = (const float*)d_in[1];
  const float* feat1 = (const float*)d_in[2];
  const float* feat2 = (const float*)d_in[3];
  const float* W0  = (const float*)d_in[4];
  const float* b0  = (const float*)d_in[5];
  const float* g0  = (const float*)d_in[6];
  const float* be0 = (const float*)d_in[7];
  const float* W1  = (const float*)d_in[8];
  const float* b1  = (const float*)d_in[9];
  const float* g1  = (const float*)d_in[10];
  const float* be1 = (const float*)d_in[11];
  float* out = (float*)d_out;

  // workspace layout (~139 MB)
  char* ws = (char*)d_ws;
  size_t off = 0;
  float* interp = (float*)(ws + off); off += (size_t)MT * C2 * 4;   // 67.1 MB (reused as y1)
  float* y0     = (float*)(ws + off); off += (size_t)MT * H0 * 4;   // 67.1 MB (cand aliases this)
  int*   kidx   = (int*)(ws + off);   off += (size_t)MT * 3 * 4;
  float* kw     = (float*)(ws + off); off += (size_t)MT * 3 * 4;
  float2* part0 = (float2*)(ws + off); off += (size_t)H0 * TM * 8;
  float2* part1 = (float2*)(ws + off); off += (size_t)H1 * TM * 8;
  float* sc0 = (float*)(ws + off); off += H0 * 4;
  float* sh0 = (float*)(ws + off); off += H0 * 4;
  float* sc1 = (float*)(ws + off); off += H1 * 4;
  float* sh1 = (float*)(ws + off); off += H1 * 4;
  float* y1 = interp;          // interp is dead after gemm0 -> alias
  float2* cand = (float2*)y0;  // cand (12.6 MB) dead before gemm0 writes y0 -> alias

  knn_chunk_kernel<<<dim3(NP1 / 256, NB, NCHUNK), 256, 0, stream>>>(xyz1, xyz2, cand);
  knn_merge_kernel<<<dim3(MT / 256), 256, 0, stream>>>(cand, kidx, kw);
  interp_kernel<<<dim3(MT / 4), 256, 0, stream>>>(feat2, kidx, kw, interp);
  gemm0_kernel<<<dim3(TM, H0 / 64), 256, 0, stream>>>(feat1, interp, W0, b0, y0, part0);
  bnfin_kernel<<<dim3(H0), 256, 0, stream>>>(part0, g0, be0, sc0, sh0);
  gemm1_kernel<<<dim3(TM, H1 / 64), 256, 0, stream>>>(y0, sc0, sh0, W1, b1, y1, part1);
  bnfin_kernel<<<dim3(H1), 256, 0, stream>>>(part1, g1, be1, sc1, sh1);
  bnrelu_out_kernel<<<dim3(MT * H1 / 4 / 256), 256, 0, stream>>>(y1, sc1, sh1, out);
}

// Round 3
// 173.878 us; speedup vs baseline: 2.8585x; 2.0714x over previous
//
#include <hip/hip_runtime.h>
#include <hip/hip_bf16.h>
#include <math.h>

// FPLayer: 3-NN inverse-distance interpolation + concat + 2x (Conv1d(k=1) -> BN(train) -> ReLU)
// B=8 N1=8192 N2=2048 C1=128 C2=256 MLP=[256,128]
// Round 3: GEMMs on bf16 MFMA (fp32 accum), fused BN0+ReLU+cast into GEMM1 staging.

#define NB 8
#define NP1 8192
#define NP2 2048
#define C1 128
#define C2 256
#define KC (C1 + C2)    // 384
#define H0 256
#define H1 128
#define MT (NB * NP1)   // 65536 rows
#define GM (MT / 128)   // 512 m-tiles
#define BN_EPS 1e-5f
#define NCHUNK 8
#define CHSZ (NP2 / NCHUNK)   // 256
#define LP 72           // padded LDS K-stride (ushorts): 144B rows -> 2-way bank alias (free)

typedef __attribute__((ext_vector_type(8))) short bf16x8;
typedef __attribute__((ext_vector_type(4))) float f32x4;
typedef __attribute__((ext_vector_type(8))) unsigned short ushort8v;
typedef __attribute__((ext_vector_type(4))) unsigned short ushort4v;

__device__ __forceinline__ unsigned short bf16_rne(float x) {
  unsigned int u = __float_as_uint(x);
  u += 0x7FFFu + ((u >> 16) & 1u);   // round-to-nearest-even on bf16 boundary
  return (unsigned short)(u >> 16);
}

// ---------------- KNN phase 1: per-chunk top-3 candidates ----------------
__global__ __launch_bounds__(256) void knn_chunk_kernel(
    const float* __restrict__ xyz1, const float* __restrict__ xyz2,
    float2* __restrict__ cand)
{
  __shared__ __align__(16) float4 s2[CHSZ];   // {x, y, z, |p|^2}  4 KB
  const int b = blockIdx.y, c = blockIdx.z;
  const float* p2 = xyz2 + ((size_t)b * NP2 + c * CHSZ) * 3;
  {
    const int j = threadIdx.x;   // CHSZ == blockDim
    float x = p2[j * 3 + 0], y = p2[j * 3 + 1], z = p2[j * 3 + 2];
    float sq = __fadd_rn(__fadd_rn(__fmul_rn(x, x), __fmul_rn(y, y)), __fmul_rn(z, z));
    s2[j] = make_float4(x, y, z, sq);
  }
  __syncthreads();
  const int n = blockIdx.x * 256 + threadIdx.x;
  const float* p1 = xyz1 + ((size_t)b * NP1 + n) * 3;
  const float ax = p1[0], ay = p1[1], az = p1[2];
  const float sq1 = __fadd_rn(__fadd_rn(__fmul_rn(ax, ax), __fmul_rn(ay, ay)), __fmul_rn(az, az));
  float b0v = 3.4e38f, b1v = 3.4e38f, b2v = 3.4e38f;
  int i0 = 0, i1 = 0, i2 = 0;
  #pragma unroll 4
  for (int j = 0; j < CHSZ; ++j) {
    float4 p = s2[j];
    float dot = __fadd_rn(__fadd_rn(__fmul_rn(ax, p.x), __fmul_rn(ay, p.y)), __fmul_rn(az, p.z));
    float d2 = __fsub_rn(__fadd_rn(sq1, p.w), __fmul_rn(2.0f, dot));
    d2 = fmaxf(d2, 1e-12f);
    if (d2 < b2v) {
      if (d2 < b1v) {
        b2v = b1v; i2 = i1;
        if (d2 < b0v) { b1v = b0v; i1 = i0; b0v = d2; i0 = j; }
        else          { b1v = d2; i1 = j; }
      } else { b2v = d2; i2 = j; }
    }
  }
  const int jb = c * CHSZ;
  const size_t o = (((size_t)b * NP1 + n) * NCHUNK + c) * 3;
  cand[o + 0] = make_float2(b0v, __int_as_float(jb + i0));
  cand[o + 1] = make_float2(b1v, __int_as_float(jb + i1));
  cand[o + 2] = make_float2(b2v, __int_as_float(jb + i2));
}

// ---------------- KNN phase 2: merge 8x3 candidates, compute weights ----------------
__global__ __launch_bounds__(256) void knn_merge_kernel(
    const float2* __restrict__ cand, int* __restrict__ knn_idx, float* __restrict__ knn_w)
{
  const int m = blockIdx.x * 256 + threadIdx.x;
  const float2* cc = cand + (size_t)m * (NCHUNK * 3);
  float b0v = 3.4e38f, b1v = 3.4e38f, b2v = 3.4e38f;
  int i0 = 0, i1 = 0, i2 = 0;
  #pragma unroll
  for (int t = 0; t < NCHUNK * 3; ++t) {
    const float2 p = cc[t];
    const float d2 = p.x;
    const int j = __float_as_int(p.y);
    if (d2 < b2v) {
      if (d2 < b1v) {
        b2v = b1v; i2 = i1;
        if (d2 < b0v) { b1v = b0v; i1 = i0; b0v = d2; i0 = j; }
        else          { b1v = d2; i1 = j; }
      } else { b2v = d2; i2 = j; }
    }
  }
  const float s0 = sqrtf(b0v), s1 = sqrtf(b1v), s2d = sqrtf(b2v);
  const float r0 = 1.0f / (s0 + 1e-8f), r1 = 1.0f / (s1 + 1e-8f), r2 = 1.0f / (s2d + 1e-8f);
  const float rs = __fadd_rn(__fadd_rn(r0, r1), r2);
  const size_t o = (size_t)m * 3;
  knn_idx[o] = i0; knn_idx[o + 1] = i1; knn_idx[o + 2] = i2;
  knn_w[o] = r0 / rs; knn_w[o + 1] = r1 / rs; knn_w[o + 2] = r2 / rs;
}

// ---------------- feat1 -> bf16 into xcat[:, 0:128] ----------------
__global__ __launch_bounds__(256) void feat1_to_xcat_kernel(
    const float* __restrict__ feat1, unsigned short* __restrict__ xcat)
{
  const int i = blockIdx.x * 256 + threadIdx.x;   // ushort8 unit id, 16 per row
  const int r = i >> 4, s = i & 15;
  const float* src = feat1 + (size_t)r * C1 + s * 8;
  const float4 a = *(const float4*)src, b = *(const float4*)(src + 4);
  ushort8v u;
  u[0] = bf16_rne(a.x); u[1] = bf16_rne(a.y); u[2] = bf16_rne(a.z); u[3] = bf16_rne(a.w);
  u[4] = bf16_rne(b.x); u[5] = bf16_rne(b.y); u[6] = bf16_rne(b.z); u[7] = bf16_rne(b.w);
  *(ushort8v*)(xcat + (size_t)r * KC + s * 8) = u;
}

// ---------------- Interpolate -> bf16 into xcat[:, 128:384] ----------------
__global__ __launch_bounds__(256) void interp_kernel(
    const float* __restrict__ feat2, const int* __restrict__ knn_idx,
    const float* __restrict__ knn_w, unsigned short* __restrict__ xcat)
{
  const int m  = blockIdx.x * 4 + (threadIdx.x >> 6);  // 4 points per block
  const int c4 = threadIdx.x & 63;                     // float4 channel slot (256/4)
  const int b  = m >> 13;
  const size_t o = (size_t)m * 3;
  const int i0 = knn_idx[o], i1 = knn_idx[o + 1], i2 = knn_idx[o + 2];
  const float w0 = knn_w[o], w1 = knn_w[o + 1], w2 = knn_w[o + 2];
  const float4* f2 = (const float4*)feat2;
  const size_t base = (size_t)b * NP2 * (C2 / 4);
  float4 f0 = f2[base + (size_t)i0 * (C2 / 4) + c4];
  float4 f1 = f2[base + (size_t)i1 * (C2 / 4) + c4];
  float4 fv = f2[base + (size_t)i2 * (C2 / 4) + c4];
  ushort4v u;
  u[0] = bf16_rne(w0 * f0.x + w1 * f1.x + w2 * fv.x);
  u[1] = bf16_rne(w0 * f0.y + w1 * f1.y + w2 * fv.y);
  u[2] = bf16_rne(w0 * f0.z + w1 * f1.z + w2 * fv.z);
  u[3] = bf16_rne(w0 * f0.w + w1 * f1.w + w2 * fv.w);
  *(ushort4v*)(xcat + (size_t)m * KC + C1 + c4 * 4) = u;
}

// ---------------- generic fp32 -> bf16 cast (weights) ----------------
__global__ __launch_bounds__(256) void cast_bf16_kernel(
    const float* __restrict__ src, unsigned short* __restrict__ dst, int n8)
{
  const int i = blockIdx.x * 256 + threadIdx.x;
  if (i >= n8) return;
  const float4 a = ((const float4*)src)[2 * i], b = ((const float4*)src)[2 * i + 1];
  ushort8v u;
  u[0] = bf16_rne(a.x); u[1] = bf16_rne(a.y); u[2] = bf16_rne(a.z); u[3] = bf16_rne(a.w);
  u[4] = bf16_rne(b.x); u[5] = bf16_rne(b.y); u[6] = bf16_rne(b.z); u[7] = bf16_rne(b.w);
  ((ushort8v*)dst)[i] = u;
}

// ---------------- GEMM0: y0 = xcat @ W0^T + b0 (bf16 MFMA), + BN partials ----------------
// grid (2 n-tiles, 512 m-tiles), 256 threads = 4 waves (2x2), 128x128 tile, BK=64.
__global__ __launch_bounds__(256) void gemm0_mfma_kernel(
    const unsigned short* __restrict__ xcat, const unsigned short* __restrict__ w0b,
    const float* __restrict__ b0, float* __restrict__ y0, float2* __restrict__ part0)
{
  __shared__ __align__(16) unsigned short As[128][LP];
  __shared__ __align__(16) unsigned short Bs[128][LP];
  __shared__ float sredS[4][64], sredQ[4][64];
  const int tn = blockIdx.x, tm = blockIdx.y;
  const int tid = threadIdx.x, lane = tid & 63, w = tid >> 6;
  const int wr = w >> 1, wc = w & 1;
  const int row0 = tm * 128, col0 = tn * 128;
  const int seg = tid & 7, rt = tid >> 3;
  const int ln = lane & 15, lg = lane >> 4;
  f32x4 acc[4][4] = {};
  for (int k0 = 0; k0 < KC; k0 += 64) {
    #pragma unroll
    for (int p = 0; p < 4; ++p) {
      const int r = rt + 32 * p;
      *(uint4*)&As[r][seg * 8] = *(const uint4*)(xcat + (size_t)(row0 + r) * KC + k0 + seg * 8);
      *(uint4*)&Bs[r][seg * 8] = *(const uint4*)(w0b + (size_t)(col0 + r) * KC + k0 + seg * 8);
    }
    __syncthreads();
    #pragma unroll
    for (int kb = 0; kb < 2; ++kb) {
      bf16x8 af[4], bf[4];
      #pragma unroll
      for (int i = 0; i < 4; ++i)
        af[i] = *(const bf16x8*)&As[wr * 64 + i * 16 + ln][kb * 32 + lg * 8];
      #pragma unroll
      for (int j = 0; j < 4; ++j)
        bf[j] = *(const bf16x8*)&Bs[wc * 64 + j * 16 + ln][kb * 32 + lg * 8];
      #pragma unroll
      for (int i = 0; i < 4; ++i)
        #pragma unroll
        for (int j = 0; j < 4; ++j)
          acc[i][j] = __builtin_amdgcn_mfma_f32_16x16x32_bf16(af[i], bf[j], acc[i][j], 0, 0, 0);
    }
    __syncthreads();
  }
  // epilogue: bias, store y0 fp32, per-column BN partials
  float colS[4] = {0, 0, 0, 0}, colQ[4] = {0, 0, 0, 0};
  #pragma unroll
  for (int j = 0; j < 4; ++j) {
    const int gc = col0 + wc * 64 + j * 16 + ln;
    const float bias = b0[gc];
    #pragma unroll
    for (int i = 0; i < 4; ++i) {
      const int grow = row0 + wr * 64 + i * 16 + lg * 4;
      #pragma unroll
      for (int q = 0; q < 4; ++q) {
        const float v = acc[i][j][q] + bias;
        y0[(size_t)(grow + q) * H0 + gc] = v;
        colS[j] += v; colQ[j] = fmaf(v, v, colQ[j]);
      }
    }
  }
  #pragma unroll
  for (int j = 0; j < 4; ++j) {
    colS[j] += __shfl_xor(colS[j], 16, 64);
    colS[j] += __shfl_xor(colS[j], 32, 64);
    colQ[j] += __shfl_xor(colQ[j], 16, 64);
    colQ[j] += __shfl_xor(colQ[j], 32, 64);
  }
  if (lg == 0) {
    #pragma unroll
    for (int j = 0; j < 4; ++j) { sredS[w][j * 16 + ln] = colS[j]; sredQ[w][j * 16 + ln] = colQ[j]; }
  }
  __syncthreads();
  if (tid < 128) {
    const int ch = tid >> 6, cl = tid & 63;
    const float S = sredS[ch][cl] + sredS[2 + ch][cl];
    const float Q = sredQ[ch][cl] + sredQ[2 + ch][cl];
    part0[(size_t)(col0 + tid) * GM + tm] = make_float2(S, Q);
  }
}

// ---------------- BN finalize: mean/var -> scale/shift ----------------
__global__ __launch_bounds__(256) void bnfin_kernel(
    const float2* __restrict__ part, const float* __restrict__ gamma,
    const float* __restrict__ beta, float* __restrict__ sc, float* __restrict__ sh)
{
  __shared__ float2 red[256];
  const int ch = blockIdx.x, tid = threadIdx.x;
  float s = 0.f, q = 0.f;
  for (int t = tid; t < GM; t += 256) {
    float2 p = part[(size_t)ch * GM + t];
    s += p.x; q += p.y;
  }
  red[tid] = make_float2(s, q);
  __syncthreads();
  for (int off = 128; off > 0; off >>= 1) {
    if (tid < off) { float2 o = red[tid + off]; red[tid].x += o.x; red[tid].y += o.y; }
    __syncthreads();
  }
  if (tid == 0) {
    const float mean = red[0].x / (float)MT;
    const float var  = red[0].y / (float)MT - mean * mean;
    const float scale = gamma[ch] / sqrtf(var + BN_EPS);
    sc[ch] = scale;
    sh[ch] = beta[ch] - mean * scale;
  }
}

// ---------------- GEMM1: y1 = relu(bn0(y0)) @ W1^T + b1 (bf16 MFMA), + BN partials ----------------
// grid (1, 512). BN0+ReLU+bf16-cast fused into A staging.
__global__ __launch_bounds__(256) void gemm1_mfma_kernel(
    const float* __restrict__ y0, const float* __restrict__ sc0, const float* __restrict__ sh0,
    const unsigned short* __restrict__ w1b, const float* __restrict__ b1,
    float* __restrict__ y1, float2* __restrict__ part1)
{
  __shared__ __align__(16) unsigned short As[128][LP];
  __shared__ __align__(16) unsigned short Bs[128][LP];
  __shared__ float sredS[4][64], sredQ[4][64];
  const int tm = blockIdx.y;
  const int tid = threadIdx.x, lane = tid & 63, w = tid >> 6;
  const int wr = w >> 1, wc = w & 1;
  const int row0 = tm * 128;
  const int seg = tid & 7, rt = tid >> 3;
  const int ln = lane & 15, lg = lane >> 4;
  f32x4 acc[4][4] = {};
  for (int k0 = 0; k0 < H0; k0 += 64) {
    const float4 sA = *(const float4*)(sc0 + k0 + seg * 8);
    const float4 sB = *(const float4*)(sc0 + k0 + seg * 8 + 4);
    const float4 hA = *(const float4*)(sh0 + k0 + seg * 8);
    const float4 hB = *(const float4*)(sh0 + k0 + seg * 8 + 4);
    #pragma unroll
    for (int p = 0; p < 4; ++p) {
      const int r = rt + 32 * p;
      const float* src = y0 + (size_t)(row0 + r) * H0 + k0 + seg * 8;
      const float4 va = *(const float4*)src, vb = *(const float4*)(src + 4);
      ushort8v u;
      u[0] = bf16_rne(fmaxf(fmaf(va.x, sA.x, hA.x), 0.f));
      u[1] = bf16_rne(fmaxf(fmaf(va.y, sA.y, hA.y), 0.f));
      u[2] = bf16_rne(fmaxf(fmaf(va.z, sA.z, hA.z), 0.f));
      u[3] = bf16_rne(fmaxf(fmaf(va.w, sA.w, hA.w), 0.f));
      u[4] = bf16_rne(fmaxf(fmaf(vb.x, sB.x, hB.x), 0.f));
      u[5] = bf16_rne(fmaxf(fmaf(vb.y, sB.y, hB.y), 0.f));
      u[6] = bf16_rne(fmaxf(fmaf(vb.z, sB.z, hB.z), 0.f));
      u[7] = bf16_rne(fmaxf(fmaf(vb.w, sB.w, hB.w), 0.f));
      *(ushort8v*)&As[r][seg * 8] = u;
      *(uint4*)&Bs[r][seg * 8] = *(const uint4*)(w1b + (size_t)r * H0 + k0 + seg * 8);
    }
    __syncthreads();
    #pragma unroll
    for (int kb = 0; kb < 2; ++kb) {
      bf16x8 af[4], bf[4];
      #pragma unroll
      for (int i = 0; i < 4; ++i)
        af[i] = *(const bf16x8*)&As[wr * 64 + i * 16 + ln][kb * 32 + lg * 8];
      #pragma unroll
      for (int j = 0; j < 4; ++j)
        bf[j] = *(const bf16x8*)&Bs[wc * 64 + j * 16 + ln][kb * 32 + lg * 8];
      #pragma unroll
      for (int i = 0; i < 4; ++i)
        #pragma unroll
        for (int j = 0; j < 4; ++j)
          acc[i][j] = __builtin_amdgcn_mfma_f32_16x16x32_bf16(af[i], bf[j], acc[i][j], 0, 0, 0);
    }
    __syncthreads();
  }
  float colS[4] = {0, 0, 0, 0}, colQ[4] = {0, 0, 0, 0};
  #pragma unroll
  for (int j = 0; j < 4; ++j) {
    const int gc = wc * 64 + j * 16 + ln;
    const float bias = b1[gc];
    #pragma unroll
    for (int i = 0; i < 4; ++i) {
      const int grow = row0 + wr * 64 + i * 16 + lg * 4;
      #pragma unroll
      for (int q = 0; q < 4; ++q) {
        const float v = acc[i][j][q] + bias;
        y1[(size_t)(grow + q) * H1 + gc] = v;
        colS[j] += v; colQ[j] = fmaf(v, v, colQ[j]);
      }
    }
  }
  #pragma unroll
  for (int j = 0; j < 4; ++j) {
    colS[j] += __shfl_xor(colS[j], 16, 64);
    colS[j] += __shfl_xor(colS[j], 32, 64);
    colQ[j] += __shfl_xor(colQ[j], 16, 64);
    colQ[j] += __shfl_xor(colQ[j], 32, 64);
  }
  if (lg == 0) {
    #pragma unroll
    for (int j = 0; j < 4; ++j) { sredS[w][j * 16 + ln] = colS[j]; sredQ[w][j * 16 + ln] = colQ[j]; }
  }
  __syncthreads();
  if (tid < 128) {
    const int ch = tid >> 6, cl = tid & 63;
    const float S = sredS[ch][cl] + sredS[2 + ch][cl];
    const float Q = sredQ[ch][cl] + sredQ[2 + ch][cl];
    part1[(size_t)tid * GM + tm] = make_float2(S, Q);
  }
}

// ---------------- Final BN1 + ReLU ----------------
__global__ __launch_bounds__(256) void bnrelu_out_kernel(
    const float* __restrict__ y1, const float* __restrict__ sc1,
    const float* __restrict__ sh1, float* __restrict__ out)
{
  const size_t i = (size_t)blockIdx.x * 256 + threadIdx.x;  // float4 index
  const int c4 = (int)(i & (H1 / 4 - 1));
  float4 v = ((const float4*)y1)[i];
  const float4 s = ((const float4*)sc1)[c4];
  const float4 h = ((const float4*)sh1)[c4];
  v.x = fmaxf(fmaf(v.x, s.x, h.x), 0.f);
  v.y = fmaxf(fmaf(v.y, s.y, h.y), 0.f);
  v.z = fmaxf(fmaf(v.z, s.z, h.z), 0.f);
  v.w = fmaxf(fmaf(v.w, s.w, h.w), 0.f);
  ((float4*)out)[i] = v;
}

extern "C" void kernel_launch(void* const* d_in, const int* in_sizes, int n_in,
                              void* d_out, int out_size, void* d_ws, size_t ws_size,
                              hipStream_t stream)
{
  const float* xyz1  = (const float*)d_in[0];
  const float* xyz2  = (const float*)d_in[1];
  const float* feat1 = (const float*)d_in[2];
  const float* feat2 = (const float*)d_in[3];
  const float* W0  = (const float*)d_in[4];
  const float* b0  = (const float*)d_in[5];
  const float* g0  = (const float*)d_in[6];
  const float* be0 = (const float*)d_in[7];
  const float* W1  = (const float*)d_in[8];
  const float* b1  = (const float*)d_in[9];
  const float* g1  = (const float*)d_in[10];
  const float* be1 = (const float*)d_in[11];
  float* out = (float*)d_out;

  // workspace layout (~121 MB)
  char* ws = (char*)d_ws;
  size_t off = 0;
  unsigned short* xcat = (unsigned short*)(ws + off); off += (size_t)MT * KC * 2;  // 50.3 MB (y1 aliases)
  float* y0 = (float*)(ws + off); off += (size_t)MT * H0 * 4;                      // 67.1 MB (cand aliases)
  int*   kidx = (int*)(ws + off);  off += (size_t)MT * 3 * 4;
  float* kw   = (float*)(ws + off); off += (size_t)MT * 3 * 4;
  float2* part0 = (float2*)(ws + off); off += (size_t)H0 * GM * 8;
  float2* part1 = (float2*)(ws + off); off += (size_t)H1 * GM * 8;
  unsigned short* w0b = (unsigned short*)(ws + off); off += (size_t)H0 * KC * 2;
  unsigned short* w1b = (unsigned short*)(ws + off); off += (size_t)H1 * H0 * 2;
  float* sc0 = (float*)(ws + off); off += H0 * 4;
  float* sh0 = (float*)(ws + off); off += H0 * 4;
  float* sc1 = (float*)(ws + off); off += H1 * 4;
  float* sh1 = (float*)(ws + off); off += H1 * 4;
  float* y1 = (float*)xcat;    // xcat dead after gemm0 -> alias
  float2* cand = (float2*)y0;  // cand dead before gemm0 writes y0 -> alias

  knn_chunk_kernel<<<dim3(NP1 / 256, NB, NCHUNK), 256, 0, stream>>>(xyz1, xyz2, cand);
  knn_merge_kernel<<<dim3(MT / 256), 256, 0, stream>>>(cand, kidx, kw);
  feat1_to_xcat_kernel<<<dim3(MT * (C1 / 8) / 256), 256, 0, stream>>>(feat1, xcat);
  interp_kernel<<<dim3(MT / 4), 256, 0, stream>>>(feat2, kidx, kw, xcat);
  cast_bf16_kernel<<<dim3((H0 * KC / 8 + 255) / 256), 256, 0, stream>>>(W0, w0b, H0 * KC / 8);
  cast_bf16_kernel<<<dim3((H1 * H0 / 8 + 255) / 256), 256, 0, stream>>>(W1, w1b, H1 * H0 / 8);
  gemm0_mfma_kernel<<<dim3(H0 / 128, GM), 256, 0, stream>>>(xcat, w0b, b0, y0, part0);
  bnfin_kernel<<<dim3(H0), 256, 0, stream>>>(part0, g0, be0, sc0, sh0);
  gemm1_mfma_kernel<<<dim3(1, GM), 256, 0, stream>>>(y0, sc0, sh0, w1b, b1, y1, part1);
  bnfin_kernel<<<dim3(H1), 256, 0, stream>>>(part1, g1, be1, sc1, sh1);
  bnrelu_out_kernel<<<dim3(MT * H1 / 4 / 256), 256, 0, stream>>>(y1, sc1, sh1, out);
}

// Round 4
// 171.600 us; speedup vs baseline: 2.8964x; 1.0133x over previous
//
#include <hip/hip_runtime.h>
#include <hip/hip_bf16.h>
#include <math.h>

// FPLayer: 3-NN inverse-distance interpolation + concat + 2x (Conv1d(k=1) -> BN(train) -> ReLU)
// B=8 N1=8192 N2=2048 C1=128 C2=256 MLP=[256,128]
// Round 4: flat predicated knn insertion; feat1 cast fused into gemm0 staging; y1 in bf16.

#define NB 8
#define NP1 8192
#define NP2 2048
#define C1 128
#define C2 256
#define KC (C1 + C2)    // 384
#define H0 256
#define H1 128
#define MT (NB * NP1)   // 65536 rows
#define GM (MT / 128)   // 512 m-tiles
#define BN_EPS 1e-5f
#define NCHUNK 8
#define CHSZ (NP2 / NCHUNK)   // 256
#define LP 72           // padded LDS K-stride (ushorts): 144B rows -> 2-way bank alias (free)

typedef __attribute__((ext_vector_type(8))) short bf16x8;
typedef __attribute__((ext_vector_type(4))) float f32x4;
typedef __attribute__((ext_vector_type(8))) unsigned short ushort8v;
typedef __attribute__((ext_vector_type(4))) unsigned short ushort4v;

__device__ __forceinline__ unsigned short bf16_rne(float x) {
  unsigned int u = __float_as_uint(x);
  u += 0x7FFFu + ((u >> 16) & 1u);   // round-to-nearest-even on bf16 boundary
  return (unsigned short)(u >> 16);
}
__device__ __forceinline__ float bf16_to_f32(unsigned short u) {
  return __uint_as_float(((unsigned int)u) << 16);
}

// ---------------- KNN phase 1: per-chunk top-3 candidates (flat predicated) ----------------
__global__ __launch_bounds__(256) void knn_chunk_kernel(
    const float* __restrict__ xyz1, const float* __restrict__ xyz2,
    float2* __restrict__ cand)
{
  __shared__ __align__(16) float4 s2[CHSZ];   // {x, y, z, |p|^2}  4 KB
  const int b = blockIdx.y, c = blockIdx.z;
  const float* p2 = xyz2 + ((size_t)b * NP2 + c * CHSZ) * 3;
  {
    const int j = threadIdx.x;   // CHSZ == blockDim
    float x = p2[j * 3 + 0], y = p2[j * 3 + 1], z = p2[j * 3 + 2];
    float sq = __fadd_rn(__fadd_rn(__fmul_rn(x, x), __fmul_rn(y, y)), __fmul_rn(z, z));
    s2[j] = make_float4(x, y, z, sq);
  }
  __syncthreads();
  const int n = blockIdx.x * 256 + threadIdx.x;
  const float* p1 = xyz1 + ((size_t)b * NP1 + n) * 3;
  const float ax = p1[0], ay = p1[1], az = p1[2];
  const float sq1 = __fadd_rn(__fadd_rn(__fmul_rn(ax, ax), __fmul_rn(ay, ay)), __fmul_rn(az, az));
  float b0v = 3.4e38f, b1v = 3.4e38f, b2v = 3.4e38f;
  int i0 = 0, i1 = 0, i2 = 0;
  // flat predicated top-3 insert: identical to sequential strict-< insertion
  // (all RHS read pre-update values; update order 2 -> 1 -> 0)
  #pragma unroll 8
  for (int j = 0; j < CHSZ; ++j) {
    const float4 p = s2[j];
    const float dot = __fadd_rn(__fadd_rn(__fmul_rn(ax, p.x), __fmul_rn(ay, p.y)), __fmul_rn(az, p.z));
    float d2 = __fsub_rn(__fadd_rn(sq1, p.w), __fmul_rn(2.0f, dot));
    d2 = fmaxf(d2, 1e-12f);
    const bool lt2 = d2 < b2v, lt1 = d2 < b1v, lt0 = d2 < b0v;
    b2v = lt1 ? b1v : (lt2 ? d2 : b2v);
    i2  = lt1 ? i1  : (lt2 ? j  : i2);
    b1v = lt0 ? b0v : (lt1 ? d2 : b1v);
    i1  = lt0 ? i0  : (lt1 ? j  : i1);
    b0v = lt0 ? d2 : b0v;
    i0  = lt0 ? j  : i0;
  }
  const int jb = c * CHSZ;
  const size_t o = (((size_t)b * NP1 + n) * NCHUNK + c) * 3;
  cand[o + 0] = make_float2(b0v, __int_as_float(jb + i0));
  cand[o + 1] = make_float2(b1v, __int_as_float(jb + i1));
  cand[o + 2] = make_float2(b2v, __int_as_float(jb + i2));
}

// ---------------- KNN phase 2: merge 8x3 candidates, compute weights ----------------
__global__ __launch_bounds__(256) void knn_merge_kernel(
    const float2* __restrict__ cand, int* __restrict__ knn_idx, float* __restrict__ knn_w)
{
  const int m = blockIdx.x * 256 + threadIdx.x;
  const float2* cc = cand + (size_t)m * (NCHUNK * 3);
  float b0v = 3.4e38f, b1v = 3.4e38f, b2v = 3.4e38f;
  int i0 = 0, i1 = 0, i2 = 0;
  #pragma unroll
  for (int t = 0; t < NCHUNK * 3; ++t) {
    const float2 p = cc[t];
    const float d2 = p.x;
    const int j = __float_as_int(p.y);
    const bool lt2 = d2 < b2v, lt1 = d2 < b1v, lt0 = d2 < b0v;
    b2v = lt1 ? b1v : (lt2 ? d2 : b2v);
    i2  = lt1 ? i1  : (lt2 ? j  : i2);
    b1v = lt0 ? b0v : (lt1 ? d2 : b1v);
    i1  = lt0 ? i0  : (lt1 ? j  : i1);
    b0v = lt0 ? d2 : b0v;
    i0  = lt0 ? j  : i0;
  }
  const float s0 = sqrtf(b0v), s1 = sqrtf(b1v), s2d = sqrtf(b2v);
  const float r0 = 1.0f / (s0 + 1e-8f), r1 = 1.0f / (s1 + 1e-8f), r2 = 1.0f / (s2d + 1e-8f);
  const float rs = __fadd_rn(__fadd_rn(r0, r1), r2);
  const size_t o = (size_t)m * 3;
  knn_idx[o] = i0; knn_idx[o + 1] = i1; knn_idx[o + 2] = i2;
  knn_w[o] = r0 / rs; knn_w[o + 1] = r1 / rs; knn_w[o + 2] = r2 / rs;
}

// ---------------- Interpolate -> dense bf16 buffer fint[MT][C2] ----------------
__global__ __launch_bounds__(256) void interp_kernel(
    const float* __restrict__ feat2, const int* __restrict__ knn_idx,
    const float* __restrict__ knn_w, unsigned short* __restrict__ fint)
{
  const int m  = blockIdx.x * 4 + (threadIdx.x >> 6);  // 4 points per block
  const int c4 = threadIdx.x & 63;                     // float4 channel slot (256/4)
  const int b  = m >> 13;
  const size_t o = (size_t)m * 3;
  const int i0 = knn_idx[o], i1 = knn_idx[o + 1], i2 = knn_idx[o + 2];
  const float w0 = knn_w[o], w1 = knn_w[o + 1], w2 = knn_w[o + 2];
  const float4* f2 = (const float4*)feat2;
  const size_t base = (size_t)b * NP2 * (C2 / 4);
  float4 f0 = f2[base + (size_t)i0 * (C2 / 4) + c4];
  float4 f1 = f2[base + (size_t)i1 * (C2 / 4) + c4];
  float4 fv = f2[base + (size_t)i2 * (C2 / 4) + c4];
  ushort4v u;
  u[0] = bf16_rne(w0 * f0.x + w1 * f1.x + w2 * fv.x);
  u[1] = bf16_rne(w0 * f0.y + w1 * f1.y + w2 * fv.y);
  u[2] = bf16_rne(w0 * f0.z + w1 * f1.z + w2 * fv.z);
  u[3] = bf16_rne(w0 * f0.w + w1 * f1.w + w2 * fv.w);
  *(ushort4v*)(fint + (size_t)m * C2 + c4 * 4) = u;
}

// ---------------- generic fp32 -> bf16 cast (weights) ----------------
__global__ __launch_bounds__(256) void cast_bf16_kernel(
    const float* __restrict__ src, unsigned short* __restrict__ dst, int n8)
{
  const int i = blockIdx.x * 256 + threadIdx.x;
  if (i >= n8) return;
  const float4 a = ((const float4*)src)[2 * i], b = ((const float4*)src)[2 * i + 1];
  ushort8v u;
  u[0] = bf16_rne(a.x); u[1] = bf16_rne(a.y); u[2] = bf16_rne(a.z); u[3] = bf16_rne(a.w);
  u[4] = bf16_rne(b.x); u[5] = bf16_rne(b.y); u[6] = bf16_rne(b.z); u[7] = bf16_rne(b.w);
  ((ushort8v*)dst)[i] = u;
}

// ---------------- GEMM0: y0 = [feat1|interp] @ W0^T + b0 (bf16 MFMA), + BN partials ----------------
// grid (2 n-tiles, 512 m-tiles), 256 threads = 4 waves (2x2), 128x128 tile, BK=64.
// feat1 is read fp32 and converted during staging (k0 < C1); interp from fint bf16.
__global__ __launch_bounds__(256) void gemm0_mfma_kernel(
    const float* __restrict__ feat1, const unsigned short* __restrict__ fint,
    const unsigned short* __restrict__ w0b, const float* __restrict__ b0,
    float* __restrict__ y0, float2* __restrict__ part0)
{
  __shared__ __align__(16) unsigned short As[128][LP];
  __shared__ __align__(16) unsigned short Bs[128][LP];
  __shared__ float sredS[4][64], sredQ[4][64];
  const int tn = blockIdx.x, tm = blockIdx.y;
  const int tid = threadIdx.x, lane = tid & 63, w = tid >> 6;
  const int wr = w >> 1, wc = w & 1;
  const int row0 = tm * 128, col0 = tn * 128;
  const int seg = tid & 7, rt = tid >> 3;
  const int ln = lane & 15, lg = lane >> 4;
  f32x4 acc[4][4] = {};
  for (int k0 = 0; k0 < KC; k0 += 64) {
    if (k0 < C1) {   // feat1 fp32 -> bf16 staging
      #pragma unroll
      for (int p = 0; p < 4; ++p) {
        const int r = rt + 32 * p;
        const float* src = feat1 + (size_t)(row0 + r) * C1 + k0 + seg * 8;
        const float4 va = *(const float4*)src, vb = *(const float4*)(src + 4);
        ushort8v u;
        u[0] = bf16_rne(va.x); u[1] = bf16_rne(va.y); u[2] = bf16_rne(va.z); u[3] = bf16_rne(va.w);
        u[4] = bf16_rne(vb.x); u[5] = bf16_rne(vb.y); u[6] = bf16_rne(vb.z); u[7] = bf16_rne(vb.w);
        *(ushort8v*)&As[r][seg * 8] = u;
        *(uint4*)&Bs[r][seg * 8] = *(const uint4*)(w0b + (size_t)(col0 + r) * KC + k0 + seg * 8);
      }
    } else {         // interp bf16 staging
      #pragma unroll
      for (int p = 0; p < 4; ++p) {
        const int r = rt + 32 * p;
        *(uint4*)&As[r][seg * 8] = *(const uint4*)(fint + (size_t)(row0 + r) * C2 + (k0 - C1) + seg * 8);
        *(uint4*)&Bs[r][seg * 8] = *(const uint4*)(w0b + (size_t)(col0 + r) * KC + k0 + seg * 8);
      }
    }
    __syncthreads();
    #pragma unroll
    for (int kb = 0; kb < 2; ++kb) {
      bf16x8 af[4], bf[4];
      #pragma unroll
      for (int i = 0; i < 4; ++i)
        af[i] = *(const bf16x8*)&As[wr * 64 + i * 16 + ln][kb * 32 + lg * 8];
      #pragma unroll
      for (int j = 0; j < 4; ++j)
        bf[j] = *(const bf16x8*)&Bs[wc * 64 + j * 16 + ln][kb * 32 + lg * 8];
      #pragma unroll
      for (int i = 0; i < 4; ++i)
        #pragma unroll
        for (int j = 0; j < 4; ++j)
          acc[i][j] = __builtin_amdgcn_mfma_f32_16x16x32_bf16(af[i], bf[j], acc[i][j], 0, 0, 0);
    }
    __syncthreads();
  }
  // epilogue: bias, store y0 fp32, per-column BN partials
  float colS[4] = {0, 0, 0, 0}, colQ[4] = {0, 0, 0, 0};
  #pragma unroll
  for (int j = 0; j < 4; ++j) {
    const int gc = col0 + wc * 64 + j * 16 + ln;
    const float bias = b0[gc];
    #pragma unroll
    for (int i = 0; i < 4; ++i) {
      const int grow = row0 + wr * 64 + i * 16 + lg * 4;
      #pragma unroll
      for (int q = 0; q < 4; ++q) {
        const float v = acc[i][j][q] + bias;
        y0[(size_t)(grow + q) * H0 + gc] = v;
        colS[j] += v; colQ[j] = fmaf(v, v, colQ[j]);
      }
    }
  }
  #pragma unroll
  for (int j = 0; j < 4; ++j) {
    colS[j] += __shfl_xor(colS[j], 16, 64);
    colS[j] += __shfl_xor(colS[j], 32, 64);
    colQ[j] += __shfl_xor(colQ[j], 16, 64);
    colQ[j] += __shfl_xor(colQ[j], 32, 64);
  }
  if (lg == 0) {
    #pragma unroll
    for (int j = 0; j < 4; ++j) { sredS[w][j * 16 + ln] = colS[j]; sredQ[w][j * 16 + ln] = colQ[j]; }
  }
  __syncthreads();
  if (tid < 128) {
    const int ch = tid >> 6, cl = tid & 63;
    const float S = sredS[ch][cl] + sredS[2 + ch][cl];
    const float Q = sredQ[ch][cl] + sredQ[2 + ch][cl];
    part0[(size_t)(col0 + tid) * GM + tm] = make_float2(S, Q);
  }
}

// ---------------- BN finalize: mean/var -> scale/shift ----------------
__global__ __launch_bounds__(256) void bnfin_kernel(
    const float2* __restrict__ part, const float* __restrict__ gamma,
    const float* __restrict__ beta, float* __restrict__ sc, float* __restrict__ sh)
{
  __shared__ float2 red[256];
  const int ch = blockIdx.x, tid = threadIdx.x;
  float s = 0.f, q = 0.f;
  for (int t = tid; t < GM; t += 256) {
    float2 p = part[(size_t)ch * GM + t];
    s += p.x; q += p.y;
  }
  red[tid] = make_float2(s, q);
  __syncthreads();
  for (int off = 128; off > 0; off >>= 1) {
    if (tid < off) { float2 o = red[tid + off]; red[tid].x += o.x; red[tid].y += o.y; }
    __syncthreads();
  }
  if (tid == 0) {
    const float mean = red[0].x / (float)MT;
    const float var  = red[0].y / (float)MT - mean * mean;
    const float scale = gamma[ch] / sqrtf(var + BN_EPS);
    sc[ch] = scale;
    sh[ch] = beta[ch] - mean * scale;
  }
}

// ---------------- GEMM1: y1 = relu(bn0(y0)) @ W1^T + b1 (bf16 MFMA), y1 stored bf16 ----------------
// grid (1, 512). BN0+ReLU+bf16-cast fused into A staging; BN1 partials from fp32 accs.
__global__ __launch_bounds__(256) void gemm1_mfma_kernel(
    const float* __restrict__ y0, const float* __restrict__ sc0, const float* __restrict__ sh0,
    const unsigned short* __restrict__ w1b, const float* __restrict__ b1,
    unsigned short* __restrict__ y1, float2* __restrict__ part1)
{
  __shared__ __align__(16) unsigned short As[128][LP];
  __shared__ __align__(16) unsigned short Bs[128][LP];
  __shared__ float sredS[4][64], sredQ[4][64];
  const int tm = blockIdx.y;
  const int tid = threadIdx.x, lane = tid & 63, w = tid >> 6;
  const int wr = w >> 1, wc = w & 1;
  const int row0 = tm * 128;
  const int seg = tid & 7, rt = tid >> 3;
  const int ln = lane & 15, lg = lane >> 4;
  f32x4 acc[4][4] = {};
  for (int k0 = 0; k0 < H0; k0 += 64) {
    const float4 sA = *(const float4*)(sc0 + k0 + seg * 8);
    const float4 sB = *(const float4*)(sc0 + k0 + seg * 8 + 4);
    const float4 hA = *(const float4*)(sh0 + k0 + seg * 8);
    const float4 hB = *(const float4*)(sh0 + k0 + seg * 8 + 4);
    #pragma unroll
    for (int p = 0; p < 4; ++p) {
      const int r = rt + 32 * p;
      const float* src = y0 + (size_t)(row0 + r) * H0 + k0 + seg * 8;
      const float4 va = *(const float4*)src, vb = *(const float4*)(src + 4);
      ushort8v u;
      u[0] = bf16_rne(fmaxf(fmaf(va.x, sA.x, hA.x), 0.f));
      u[1] = bf16_rne(fmaxf(fmaf(va.y, sA.y, hA.y), 0.f));
      u[2] = bf16_rne(fmaxf(fmaf(va.z, sA.z, hA.z), 0.f));
      u[3] = bf16_rne(fmaxf(fmaf(va.w, sA.w, hA.w), 0.f));
      u[4] = bf16_rne(fmaxf(fmaf(vb.x, sB.x, hB.x), 0.f));
      u[5] = bf16_rne(fmaxf(fmaf(vb.y, sB.y, hB.y), 0.f));
      u[6] = bf16_rne(fmaxf(fmaf(vb.z, sB.z, hB.z), 0.f));
      u[7] = bf16_rne(fmaxf(fmaf(vb.w, sB.w, hB.w), 0.f));
      *(ushort8v*)&As[r][seg * 8] = u;
      *(uint4*)&Bs[r][seg * 8] = *(const uint4*)(w1b + (size_t)r * H0 + k0 + seg * 8);
    }
    __syncthreads();
    #pragma unroll
    for (int kb = 0; kb < 2; ++kb) {
      bf16x8 af[4], bf[4];
      #pragma unroll
      for (int i = 0; i < 4; ++i)
        af[i] = *(const bf16x8*)&As[wr * 64 + i * 16 + ln][kb * 32 + lg * 8];
      #pragma unroll
      for (int j = 0; j < 4; ++j)
        bf[j] = *(const bf16x8*)&Bs[wc * 64 + j * 16 + ln][kb * 32 + lg * 8];
      #pragma unroll
      for (int i = 0; i < 4; ++i)
        #pragma unroll
        for (int j = 0; j < 4; ++j)
          acc[i][j] = __builtin_amdgcn_mfma_f32_16x16x32_bf16(af[i], bf[j], acc[i][j], 0, 0, 0);
    }
    __syncthreads();
  }
  float colS[4] = {0, 0, 0, 0}, colQ[4] = {0, 0, 0, 0};
  #pragma unroll
  for (int j = 0; j < 4; ++j) {
    const int gc = wc * 64 + j * 16 + ln;
    const float bias = b1[gc];
    #pragma unroll
    for (int i = 0; i < 4; ++i) {
      const int grow = row0 + wr * 64 + i * 16 + lg * 4;
      #pragma unroll
      for (int q = 0; q < 4; ++q) {
        const float v = acc[i][j][q] + bias;
        y1[(size_t)(grow + q) * H1 + gc] = bf16_rne(v);
        colS[j] += v; colQ[j] = fmaf(v, v, colQ[j]);
      }
    }
  }
  #pragma unroll
  for (int j = 0; j < 4; ++j) {
    colS[j] += __shfl_xor(colS[j], 16, 64);
    colS[j] += __shfl_xor(colS[j], 32, 64);
    colQ[j] += __shfl_xor(colQ[j], 16, 64);
    colQ[j] += __shfl_xor(colQ[j], 32, 64);
  }
  if (lg == 0) {
    #pragma unroll
    for (int j = 0; j < 4; ++j) { sredS[w][j * 16 + ln] = colS[j]; sredQ[w][j * 16 + ln] = colQ[j]; }
  }
  __syncthreads();
  if (tid < 128) {
    const int ch = tid >> 6, cl = tid & 63;
    const float S = sredS[ch][cl] + sredS[2 + ch][cl];
    const float Q = sredQ[ch][cl] + sredQ[2 + ch][cl];
    part1[(size_t)tid * GM + tm] = make_float2(S, Q);
  }
}

// ---------------- Final BN1 + ReLU (bf16 y1 -> fp32 out) ----------------
__global__ __launch_bounds__(256) void bnrelu_out_kernel(
    const unsigned short* __restrict__ y1, const float* __restrict__ sc1,
    const float* __restrict__ sh1, float* __restrict__ out)
{
  const size_t i = (size_t)blockIdx.x * 256 + threadIdx.x;  // ushort8 unit (8 channels)
  const int c8 = (int)(i & (H1 / 8 - 1));
  const ushort8v u = ((const ushort8v*)y1)[i];
  const float4 s0 = ((const float4*)sc1)[c8 * 2], s1 = ((const float4*)sc1)[c8 * 2 + 1];
  const float4 h0 = ((const float4*)sh1)[c8 * 2], h1 = ((const float4*)sh1)[c8 * 2 + 1];
  float4 o0, o1;
  o0.x = fmaxf(fmaf(bf16_to_f32(u[0]), s0.x, h0.x), 0.f);
  o0.y = fmaxf(fmaf(bf16_to_f32(u[1]), s0.y, h0.y), 0.f);
  o0.z = fmaxf(fmaf(bf16_to_f32(u[2]), s0.z, h0.z), 0.f);
  o0.w = fmaxf(fmaf(bf16_to_f32(u[3]), s0.w, h0.w), 0.f);
  o1.x = fmaxf(fmaf(bf16_to_f32(u[4]), s1.x, h1.x), 0.f);
  o1.y = fmaxf(fmaf(bf16_to_f32(u[5]), s1.y, h1.y), 0.f);
  o1.z = fmaxf(fmaf(bf16_to_f32(u[6]), s1.z, h1.z), 0.f);
  o1.w = fmaxf(fmaf(bf16_to_f32(u[7]), s1.w, h1.w), 0.f);
  ((float4*)out)[2 * i] = o0;
  ((float4*)out)[2 * i + 1] = o1;
}

extern "C" void kernel_launch(void* const* d_in, const int* in_sizes, int n_in,
                              void* d_out, int out_size, void* d_ws, size_t ws_size,
                              hipStream_t stream)
{
  const float* xyz1  = (const float*)d_in[0];
  const float* xyz2  = (const float*)d_in[1];
  const float* feat1 = (const float*)d_in[2];
  const float* feat2 = (const float*)d_in[3];
  const float* W0  = (const float*)d_in[4];
  const float* b0  = (const float*)d_in[5];
  const float* g0  = (const float*)d_in[6];
  const float* be0 = (const float*)d_in[7];
  const float* W1  = (const float*)d_in[8];
  const float* b1  = (const float*)d_in[9];
  const float* g1  = (const float*)d_in[10];
  const float* be1 = (const float*)d_in[11];
  float* out = (float*)d_out;

  // workspace layout (~104 MB)
  char* ws = (char*)d_ws;
  size_t off = 0;
  unsigned short* fint = (unsigned short*)(ws + off); off += (size_t)MT * C2 * 2;  // 33.5 MB (y1 aliases)
  float* y0 = (float*)(ws + off); off += (size_t)MT * H0 * 4;                      // 67.1 MB (cand aliases)
  int*   kidx = (int*)(ws + off);  off += (size_t)MT * 3 * 4;
  float* kw   = (float*)(ws + off); off += (size_t)MT * 3 * 4;
  float2* part0 = (float2*)(ws + off); off += (size_t)H0 * GM * 8;
  float2* part1 = (float2*)(ws + off); off += (size_t)H1 * GM * 8;
  unsigned short* w0b = (unsigned short*)(ws + off); off += (size_t)H0 * KC * 2;
  unsigned short* w1b = (unsigned short*)(ws + off); off += (size_t)H1 * H0 * 2;
  float* sc0 = (float*)(ws + off); off += H0 * 4;
  float* sh0 = (float*)(ws + off); off += H0 * 4;
  float* sc1 = (float*)(ws + off); off += H1 * 4;
  float* sh1 = (float*)(ws + off); off += H1 * 4;
  unsigned short* y1 = fint;   // fint dead after gemm0 -> alias
  float2* cand = (float2*)y0;  // cand dead before gemm0 writes y0 -> alias

  knn_chunk_kernel<<<dim3(NP1 / 256, NB, NCHUNK), 256, 0, stream>>>(xyz1, xyz2, cand);
  knn_merge_kernel<<<dim3(MT / 256), 256, 0, stream>>>(cand, kidx, kw);
  interp_kernel<<<dim3(MT / 4), 256, 0, stream>>>(feat2, kidx, kw, fint);
  cast_bf16_kernel<<<dim3((H0 * KC / 8 + 255) / 256), 256, 0, stream>>>(W0, w0b, H0 * KC / 8);
  cast_bf16_kernel<<<dim3((H1 * H0 / 8 + 255) / 256), 256, 0, stream>>>(W1, w1b, H1 * H0 / 8);
  gemm0_mfma_kernel<<<dim3(H0 / 128, GM), 256, 0, stream>>>(feat1, fint, w0b, b0, y0, part0);
  bnfin_kernel<<<dim3(H0), 256, 0, stream>>>(part0, g0, be0, sc0, sh0);
  gemm1_mfma_kernel<<<dim3(1, GM), 256, 0, stream>>>(y0, sc0, sh0, w1b, b1, y1, part1);
  bnfin_kernel<<<dim3(H1), 256, 0, stream>>>(part1, g1, be1, sc1, sh1);
  bnrelu_out_kernel<<<dim3(MT * H1 / 8 / 256), 256, 0, stream>>>(y1, sc1, sh1, out);
}

// Round 5
// 153.682 us; speedup vs baseline: 3.2341x; 1.1166x over previous
//
#include <hip/hip_runtime.h>
#include <hip/hip_bf16.h>
#include <math.h>

// FPLayer: 3-NN inverse-distance interpolation + concat + 2x (Conv1d(k=1) -> BN(train) -> ReLU)
// B=8 N1=8192 N2=2048 C1=128 C2=256 MLP=[256,128]
// Round 5: knn branchy (round-3 body) + NCHUNK=4 + halved-distance + hoisted clamp;
//          y0 stored bf16; merged weight casts.

#define NB 8
#define NP1 8192
#define NP2 2048
#define C1 128
#define C2 256
#define KC (C1 + C2)    // 384
#define H0 256
#define H1 128
#define MT (NB * NP1)   // 65536 rows
#define GM (MT / 128)   // 512 m-tiles
#define BN_EPS 1e-5f
#define NCHUNK 4
#define CHSZ (NP2 / NCHUNK)   // 512
#define LP 72           // padded LDS K-stride (ushorts): 144B rows -> 2-way bank alias (free)

typedef __attribute__((ext_vector_type(8))) short bf16x8;
typedef __attribute__((ext_vector_type(4))) float f32x4;
typedef __attribute__((ext_vector_type(8))) unsigned short ushort8v;
typedef __attribute__((ext_vector_type(4))) unsigned short ushort4v;

__device__ __forceinline__ unsigned short bf16_rne(float x) {
  unsigned int u = __float_as_uint(x);
  u += 0x7FFFu + ((u >> 16) & 1u);   // round-to-nearest-even on bf16 boundary
  return (unsigned short)(u >> 16);
}
__device__ __forceinline__ float bf16_to_f32(unsigned short u) {
  return __uint_as_float(((unsigned int)u) << 16);
}

// ---------------- KNN phase 1: per-chunk top-3 candidates (branchy insert) ----------------
// Values tracked are m = d2/2 (exact scaling commutes with rounding -> ordering & ties
// identical to the reference's d2). Clamp hoisted to merge (monotone, only affects d2<1e-12).
__global__ __launch_bounds__(256) void knn_chunk_kernel(
    const float* __restrict__ xyz1, const float* __restrict__ xyz2,
    float2* __restrict__ cand)
{
  __shared__ __align__(16) float4 s2[CHSZ];   // {x, y, z, |p|^2/2}  8 KB
  const int b = blockIdx.y, c = blockIdx.z;
  const float* p2 = xyz2 + ((size_t)b * NP2 + c * CHSZ) * 3;
  for (int j = threadIdx.x; j < CHSZ; j += 256) {
    float x = p2[j * 3 + 0], y = p2[j * 3 + 1], z = p2[j * 3 + 2];
    float sq = __fadd_rn(__fadd_rn(__fmul_rn(x, x), __fmul_rn(y, y)), __fmul_rn(z, z));
    s2[j] = make_float4(x, y, z, 0.5f * sq);   // /2 exact
  }
  __syncthreads();
  const int n = blockIdx.x * 256 + threadIdx.x;
  const float* p1 = xyz1 + ((size_t)b * NP1 + n) * 3;
  const float ax = p1[0], ay = p1[1], az = p1[2];
  const float sq1 = __fadd_rn(__fadd_rn(__fmul_rn(ax, ax), __fmul_rn(ay, ay)), __fmul_rn(az, az));
  const float hsq1 = 0.5f * sq1;   // exact
  float b0v = 3.4e38f, b1v = 3.4e38f, b2v = 3.4e38f;
  int i0 = 0, i1 = 0, i2 = 0;
  #pragma unroll 4
  for (int j = 0; j < CHSZ; ++j) {
    const float4 p = s2[j];
    const float dot = __fadd_rn(__fadd_rn(__fmul_rn(ax, p.x), __fmul_rn(ay, p.y)), __fmul_rn(az, p.z));
    const float m = __fsub_rn(__fadd_rn(hsq1, p.w), dot);   // = d2/2 bit-exact scaled
    if (m < b2v) {
      if (m < b1v) {
        b2v = b1v; i2 = i1;
        if (m < b0v) { b1v = b0v; i1 = i0; b0v = m; i0 = j; }
        else          { b1v = m; i1 = j; }
      } else { b2v = m; i2 = j; }
    }
  }
  const int jb = c * CHSZ;
  const size_t o = (((size_t)b * NP1 + n) * NCHUNK + c) * 3;
  cand[o + 0] = make_float2(b0v, __int_as_float(jb + i0));
  cand[o + 1] = make_float2(b1v, __int_as_float(jb + i1));
  cand[o + 2] = make_float2(b2v, __int_as_float(jb + i2));
}

// ---------------- KNN phase 2: merge 4x3 candidates, compute weights ----------------
__global__ __launch_bounds__(256) void knn_merge_kernel(
    const float2* __restrict__ cand, int* __restrict__ knn_idx, float* __restrict__ knn_w)
{
  const int m = blockIdx.x * 256 + threadIdx.x;
  const float2* cc = cand + (size_t)m * (NCHUNK * 3);
  float b0v = 3.4e38f, b1v = 3.4e38f, b2v = 3.4e38f;
  int i0 = 0, i1 = 0, i2 = 0;
  #pragma unroll
  for (int t = 0; t < NCHUNK * 3; ++t) {
    const float2 p = cc[t];
    const float d2 = p.x;
    const int j = __float_as_int(p.y);
    if (d2 < b2v) {
      if (d2 < b1v) {
        b2v = b1v; i2 = i1;
        if (d2 < b0v) { b1v = b0v; i1 = i0; b0v = d2; i0 = j; }
        else          { b1v = d2; i1 = j; }
      } else { b2v = d2; i2 = j; }
    }
  }
  // restore d2 = 2*m (exact) and apply the reference clamp before sqrt
  const float d0 = fmaxf(__fmul_rn(2.0f, b0v), 1e-12f);
  const float d1 = fmaxf(__fmul_rn(2.0f, b1v), 1e-12f);
  const float d2v = fmaxf(__fmul_rn(2.0f, b2v), 1e-12f);
  const float s0 = sqrtf(d0), s1 = sqrtf(d1), s2d = sqrtf(d2v);
  const float r0 = 1.0f / (s0 + 1e-8f), r1 = 1.0f / (s1 + 1e-8f), r2 = 1.0f / (s2d + 1e-8f);
  const float rs = __fadd_rn(__fadd_rn(r0, r1), r2);
  const size_t o = (size_t)m * 3;
  knn_idx[o] = i0; knn_idx[o + 1] = i1; knn_idx[o + 2] = i2;
  knn_w[o] = r0 / rs; knn_w[o + 1] = r1 / rs; knn_w[o + 2] = r2 / rs;
}

// ---------------- Interpolate -> dense bf16 buffer fint[MT][C2] ----------------
__global__ __launch_bounds__(256) void interp_kernel(
    const float* __restrict__ feat2, const int* __restrict__ knn_idx,
    const float* __restrict__ knn_w, unsigned short* __restrict__ fint)
{
  const int m  = blockIdx.x * 4 + (threadIdx.x >> 6);  // 4 points per block
  const int c4 = threadIdx.x & 63;                     // float4 channel slot (256/4)
  const int b  = m >> 13;
  const size_t o = (size_t)m * 3;
  const int i0 = knn_idx[o], i1 = knn_idx[o + 1], i2 = knn_idx[o + 2];
  const float w0 = knn_w[o], w1 = knn_w[o + 1], w2 = knn_w[o + 2];
  const float4* f2 = (const float4*)feat2;
  const size_t base = (size_t)b * NP2 * (C2 / 4);
  float4 f0 = f2[base + (size_t)i0 * (C2 / 4) + c4];
  float4 f1 = f2[base + (size_t)i1 * (C2 / 4) + c4];
  float4 fv = f2[base + (size_t)i2 * (C2 / 4) + c4];
  ushort4v u;
  u[0] = bf16_rne(w0 * f0.x + w1 * f1.x + w2 * fv.x);
  u[1] = bf16_rne(w0 * f0.y + w1 * f1.y + w2 * fv.y);
  u[2] = bf16_rne(w0 * f0.z + w1 * f1.z + w2 * fv.z);
  u[3] = bf16_rne(w0 * f0.w + w1 * f1.w + w2 * fv.w);
  *(ushort4v*)(fint + (size_t)m * C2 + c4 * 4) = u;
}

// ---------------- both weights fp32 -> bf16 in one launch ----------------
__global__ __launch_bounds__(256) void cast_both_kernel(
    const float* __restrict__ W0, const float* __restrict__ W1,
    unsigned short* __restrict__ w0b, unsigned short* __restrict__ w1b)
{
  const int i = blockIdx.x * 256 + threadIdx.x;
  const int n0 = H0 * KC / 8;   // 12288
  const float* src; unsigned short* dst; int k;
  if (i < n0) { src = W0; dst = w0b; k = i; }
  else        { src = W1; dst = w1b; k = i - n0; }   // n1 = 4096
  const float4 a = ((const float4*)src)[2 * k], b = ((const float4*)src)[2 * k + 1];
  ushort8v u;
  u[0] = bf16_rne(a.x); u[1] = bf16_rne(a.y); u[2] = bf16_rne(a.z); u[3] = bf16_rne(a.w);
  u[4] = bf16_rne(b.x); u[5] = bf16_rne(b.y); u[6] = bf16_rne(b.z); u[7] = bf16_rne(b.w);
  *(ushort8v*)(dst + (size_t)k * 8) = u;
}

// ---------------- GEMM0: y0 = [feat1|interp] @ W0^T + b0 (bf16 MFMA), y0 stored bf16 ----------------
// grid (2 n-tiles, 512 m-tiles), 256 threads = 4 waves (2x2), 128x128 tile, BK=64.
__global__ __launch_bounds__(256) void gemm0_mfma_kernel(
    const float* __restrict__ feat1, const unsigned short* __restrict__ fint,
    const unsigned short* __restrict__ w0b, const float* __restrict__ b0,
    unsigned short* __restrict__ y0b, float2* __restrict__ part0)
{
  __shared__ __align__(16) unsigned short As[128][LP];
  __shared__ __align__(16) unsigned short Bs[128][LP];
  __shared__ float sredS[4][64], sredQ[4][64];
  const int tn = blockIdx.x, tm = blockIdx.y;
  const int tid = threadIdx.x, lane = tid & 63, w = tid >> 6;
  const int wr = w >> 1, wc = w & 1;
  const int row0 = tm * 128, col0 = tn * 128;
  const int seg = tid & 7, rt = tid >> 3;
  const int ln = lane & 15, lg = lane >> 4;
  f32x4 acc[4][4] = {};
  for (int k0 = 0; k0 < KC; k0 += 64) {
    if (k0 < C1) {   // feat1 fp32 -> bf16 staging
      #pragma unroll
      for (int p = 0; p < 4; ++p) {
        const int r = rt + 32 * p;
        const float* src = feat1 + (size_t)(row0 + r) * C1 + k0 + seg * 8;
        const float4 va = *(const float4*)src, vb = *(const float4*)(src + 4);
        ushort8v u;
        u[0] = bf16_rne(va.x); u[1] = bf16_rne(va.y); u[2] = bf16_rne(va.z); u[3] = bf16_rne(va.w);
        u[4] = bf16_rne(vb.x); u[5] = bf16_rne(vb.y); u[6] = bf16_rne(vb.z); u[7] = bf16_rne(vb.w);
        *(ushort8v*)&As[r][seg * 8] = u;
        *(uint4*)&Bs[r][seg * 8] = *(const uint4*)(w0b + (size_t)(col0 + r) * KC + k0 + seg * 8);
      }
    } else {         // interp bf16 staging
      #pragma unroll
      for (int p = 0; p < 4; ++p) {
        const int r = rt + 32 * p;
        *(uint4*)&As[r][seg * 8] = *(const uint4*)(fint + (size_t)(row0 + r) * C2 + (k0 - C1) + seg * 8);
        *(uint4*)&Bs[r][seg * 8] = *(const uint4*)(w0b + (size_t)(col0 + r) * KC + k0 + seg * 8);
      }
    }
    __syncthreads();
    #pragma unroll
    for (int kb = 0; kb < 2; ++kb) {
      bf16x8 af[4], bf[4];
      #pragma unroll
      for (int i = 0; i < 4; ++i)
        af[i] = *(const bf16x8*)&As[wr * 64 + i * 16 + ln][kb * 32 + lg * 8];
      #pragma unroll
      for (int j = 0; j < 4; ++j)
        bf[j] = *(const bf16x8*)&Bs[wc * 64 + j * 16 + ln][kb * 32 + lg * 8];
      #pragma unroll
      for (int i = 0; i < 4; ++i)
        #pragma unroll
        for (int j = 0; j < 4; ++j)
          acc[i][j] = __builtin_amdgcn_mfma_f32_16x16x32_bf16(af[i], bf[j], acc[i][j], 0, 0, 0);
    }
    __syncthreads();
  }
  // epilogue: bias, store y0 bf16, per-column BN partials from fp32 values
  float colS[4] = {0, 0, 0, 0}, colQ[4] = {0, 0, 0, 0};
  #pragma unroll
  for (int j = 0; j < 4; ++j) {
    const int gc = col0 + wc * 64 + j * 16 + ln;
    const float bias = b0[gc];
    #pragma unroll
    for (int i = 0; i < 4; ++i) {
      const int grow = row0 + wr * 64 + i * 16 + lg * 4;
      #pragma unroll
      for (int q = 0; q < 4; ++q) {
        const float v = acc[i][j][q] + bias;
        y0b[(size_t)(grow + q) * H0 + gc] = bf16_rne(v);
        colS[j] += v; colQ[j] = fmaf(v, v, colQ[j]);
      }
    }
  }
  #pragma unroll
  for (int j = 0; j < 4; ++j) {
    colS[j] += __shfl_xor(colS[j], 16, 64);
    colS[j] += __shfl_xor(colS[j], 32, 64);
    colQ[j] += __shfl_xor(colQ[j], 16, 64);
    colQ[j] += __shfl_xor(colQ[j], 32, 64);
  }
  if (lg == 0) {
    #pragma unroll
    for (int j = 0; j < 4; ++j) { sredS[w][j * 16 + ln] = colS[j]; sredQ[w][j * 16 + ln] = colQ[j]; }
  }
  __syncthreads();
  if (tid < 128) {
    const int ch = tid >> 6, cl = tid & 63;
    const float S = sredS[ch][cl] + sredS[2 + ch][cl];
    const float Q = sredQ[ch][cl] + sredQ[2 + ch][cl];
    part0[(size_t)(col0 + tid) * GM + tm] = make_float2(S, Q);
  }
}

// ---------------- BN finalize: mean/var -> scale/shift ----------------
__global__ __launch_bounds__(256) void bnfin_kernel(
    const float2* __restrict__ part, const float* __restrict__ gamma,
    const float* __restrict__ beta, float* __restrict__ sc, float* __restrict__ sh)
{
  __shared__ float2 red[256];
  const int ch = blockIdx.x, tid = threadIdx.x;
  float s = 0.f, q = 0.f;
  for (int t = tid; t < GM; t += 256) {
    float2 p = part[(size_t)ch * GM + t];
    s += p.x; q += p.y;
  }
  red[tid] = make_float2(s, q);
  __syncthreads();
  for (int off = 128; off > 0; off >>= 1) {
    if (tid < off) { float2 o = red[tid + off]; red[tid].x += o.x; red[tid].y += o.y; }
    __syncthreads();
  }
  if (tid == 0) {
    const float mean = red[0].x / (float)MT;
    const float var  = red[0].y / (float)MT - mean * mean;
    const float scale = gamma[ch] / sqrtf(var + BN_EPS);
    sc[ch] = scale;
    sh[ch] = beta[ch] - mean * scale;
  }
}

// ---------------- GEMM1: y1 = relu(bn0(y0)) @ W1^T + b1 (bf16 MFMA), y1 stored bf16 ----------------
// grid (1, 512). BN0+ReLU+bf16-cast fused into A staging; y0 read as bf16.
__global__ __launch_bounds__(256) void gemm1_mfma_kernel(
    const unsigned short* __restrict__ y0b, const float* __restrict__ sc0, const float* __restrict__ sh0,
    const unsigned short* __restrict__ w1b, const float* __restrict__ b1,
    unsigned short* __restrict__ y1, float2* __restrict__ part1)
{
  __shared__ __align__(16) unsigned short As[128][LP];
  __shared__ __align__(16) unsigned short Bs[128][LP];
  __shared__ float sredS[4][64], sredQ[4][64];
  const int tm = blockIdx.y;
  const int tid = threadIdx.x, lane = tid & 63, w = tid >> 6;
  const int wr = w >> 1, wc = w & 1;
  const int row0 = tm * 128;
  const int seg = tid & 7, rt = tid >> 3;
  const int ln = lane & 15, lg = lane >> 4;
  f32x4 acc[4][4] = {};
  for (int k0 = 0; k0 < H0; k0 += 64) {
    const float4 sA = *(const float4*)(sc0 + k0 + seg * 8);
    const float4 sB = *(const float4*)(sc0 + k0 + seg * 8 + 4);
    const float4 hA = *(const float4*)(sh0 + k0 + seg * 8);
    const float4 hB = *(const float4*)(sh0 + k0 + seg * 8 + 4);
    #pragma unroll
    for (int p = 0; p < 4; ++p) {
      const int r = rt + 32 * p;
      const ushort8v uy = *(const ushort8v*)(y0b + (size_t)(row0 + r) * H0 + k0 + seg * 8);
      ushort8v u;
      u[0] = bf16_rne(fmaxf(fmaf(bf16_to_f32(uy[0]), sA.x, hA.x), 0.f));
      u[1] = bf16_rne(fmaxf(fmaf(bf16_to_f32(uy[1]), sA.y, hA.y), 0.f));
      u[2] = bf16_rne(fmaxf(fmaf(bf16_to_f32(uy[2]), sA.z, hA.z), 0.f));
      u[3] = bf16_rne(fmaxf(fmaf(bf16_to_f32(uy[3]), sA.w, hA.w), 0.f));
      u[4] = bf16_rne(fmaxf(fmaf(bf16_to_f32(uy[4]), sB.x, hB.x), 0.f));
      u[5] = bf16_rne(fmaxf(fmaf(bf16_to_f32(uy[5]), sB.y, hB.y), 0.f));
      u[6] = bf16_rne(fmaxf(fmaf(bf16_to_f32(uy[6]), sB.z, hB.z), 0.f));
      u[7] = bf16_rne(fmaxf(fmaf(bf16_to_f32(uy[7]), sB.w, hB.w), 0.f));
      *(ushort8v*)&As[r][seg * 8] = u;
      *(uint4*)&Bs[r][seg * 8] = *(const uint4*)(w1b + (size_t)r * H0 + k0 + seg * 8);
    }
    __syncthreads();
    #pragma unroll
    for (int kb = 0; kb < 2; ++kb) {
      bf16x8 af[4], bf[4];
      #pragma unroll
      for (int i = 0; i < 4; ++i)
        af[i] = *(const bf16x8*)&As[wr * 64 + i * 16 + ln][kb * 32 + lg * 8];
      #pragma unroll
      for (int j = 0; j < 4; ++j)
        bf[j] = *(const bf16x8*)&Bs[wc * 64 + j * 16 + ln][kb * 32 + lg * 8];
      #pragma unroll
      for (int i = 0; i < 4; ++i)
        #pragma unroll
        for (int j = 0; j < 4; ++j)
          acc[i][j] = __builtin_amdgcn_mfma_f32_16x16x32_bf16(af[i], bf[j], acc[i][j], 0, 0, 0);
    }
    __syncthreads();
  }
  float colS[4] = {0, 0, 0, 0}, colQ[4] = {0, 0, 0, 0};
  #pragma unroll
  for (int j = 0; j < 4; ++j) {
    const int gc = wc * 64 + j * 16 + ln;
    const float bias = b1[gc];
    #pragma unroll
    for (int i = 0; i < 4; ++i) {
      const int grow = row0 + wr * 64 + i * 16 + lg * 4;
      #pragma unroll
      for (int q = 0; q < 4; ++q) {
        const float v = acc[i][j][q] + bias;
        y1[(size_t)(grow + q) * H1 + gc] = bf16_rne(v);
        colS[j] += v; colQ[j] = fmaf(v, v, colQ[j]);
      }
    }
  }
  #pragma unroll
  for (int j = 0; j < 4; ++j) {
    colS[j] += __shfl_xor(colS[j], 16, 64);
    colS[j] += __shfl_xor(colS[j], 32, 64);
    colQ[j] += __shfl_xor(colQ[j], 16, 64);
    colQ[j] += __shfl_xor(colQ[j], 32, 64);
  }
  if (lg == 0) {
    #pragma unroll
    for (int j = 0; j < 4; ++j) { sredS[w][j * 16 + ln] = colS[j]; sredQ[w][j * 16 + ln] = colQ[j]; }
  }
  __syncthreads();
  if (tid < 128) {
    const int ch = tid >> 6, cl = tid & 63;
    const float S = sredS[ch][cl] + sredS[2 + ch][cl];
    const float Q = sredQ[ch][cl] + sredQ[2 + ch][cl];
    part1[(size_t)tid * GM + tm] = make_float2(S, Q);
  }
}

// ---------------- Final BN1 + ReLU (bf16 y1 -> fp32 out) ----------------
__global__ __launch_bounds__(256) void bnrelu_out_kernel(
    const unsigned short* __restrict__ y1, const float* __restrict__ sc1,
    const float* __restrict__ sh1, float* __restrict__ out)
{
  const size_t i = (size_t)blockIdx.x * 256 + threadIdx.x;  // ushort8 unit (8 channels)
  const int c8 = (int)(i & (H1 / 8 - 1));
  const ushort8v u = ((const ushort8v*)y1)[i];
  const float4 s0 = ((const float4*)sc1)[c8 * 2], s1 = ((const float4*)sc1)[c8 * 2 + 1];
  const float4 h0 = ((const float4*)sh1)[c8 * 2], h1 = ((const float4*)sh1)[c8 * 2 + 1];
  float4 o0, o1;
  o0.x = fmaxf(fmaf(bf16_to_f32(u[0]), s0.x, h0.x), 0.f);
  o0.y = fmaxf(fmaf(bf16_to_f32(u[1]), s0.y, h0.y), 0.f);
  o0.z = fmaxf(fmaf(bf16_to_f32(u[2]), s0.z, h0.z), 0.f);
  o0.w = fmaxf(fmaf(bf16_to_f32(u[3]), s0.w, h0.w), 0.f);
  o1.x = fmaxf(fmaf(bf16_to_f32(u[4]), s1.x, h1.x), 0.f);
  o1.y = fmaxf(fmaf(bf16_to_f32(u[5]), s1.y, h1.y), 0.f);
  o1.z = fmaxf(fmaf(bf16_to_f32(u[6]), s1.z, h1.z), 0.f);
  o1.w = fmaxf(fmaf(bf16_to_f32(u[7]), s1.w, h1.w), 0.f);
  ((float4*)out)[2 * i] = o0;
  ((float4*)out)[2 * i + 1] = o1;
}

extern "C" void kernel_launch(void* const* d_in, const int* in_sizes, int n_in,
                              void* d_out, int out_size, void* d_ws, size_t ws_size,
                              hipStream_t stream)
{
  const float* xyz1  = (const float*)d_in[0];
  const float* xyz2  = (const float*)d_in[1];
  const float* feat1 = (const float*)d_in[2];
  const float* feat2 = (const float*)d_in[3];
  const float* W0  = (const float*)d_in[4];
  const float* b0  = (const float*)d_in[5];
  const float* g0  = (const float*)d_in[6];
  const float* be0 = (const float*)d_in[7];
  const float* W1  = (const float*)d_in[8];
  const float* b1  = (const float*)d_in[9];
  const float* g1  = (const float*)d_in[10];
  const float* be1 = (const float*)d_in[11];
  float* out = (float*)d_out;

  // workspace layout (~71 MB)
  char* ws = (char*)d_ws;
  size_t off = 0;
  unsigned short* fint = (unsigned short*)(ws + off); off += (size_t)MT * C2 * 2;  // 33.5 MB (y1 aliases)
  unsigned short* y0b  = (unsigned short*)(ws + off); off += (size_t)MT * H0 * 2;  // 33.5 MB (cand aliases)
  int*   kidx = (int*)(ws + off);  off += (size_t)MT * 3 * 4;
  float* kw   = (float*)(ws + off); off += (size_t)MT * 3 * 4;
  float2* part0 = (float2*)(ws + off); off += (size_t)H0 * GM * 8;
  float2* part1 = (float2*)(ws + off); off += (size_t)H1 * GM * 8;
  unsigned short* w0b = (unsigned short*)(ws + off); off += (size_t)H0 * KC * 2;
  unsigned short* w1b = (unsigned short*)(ws + off); off += (size_t)H1 * H0 * 2;
  float* sc0 = (float*)(ws + off); off += H0 * 4;
  float* sh0 = (float*)(ws + off); off += H0 * 4;
  float* sc1 = (float*)(ws + off); off += H1 * 4;
  float* sh1 = (float*)(ws + off); off += H1 * 4;
  unsigned short* y1 = fint;    // fint dead after gemm0 -> alias
  float2* cand = (float2*)y0b;  // cand (6.3 MB) dead before gemm0 writes y0b -> alias

  knn_chunk_kernel<<<dim3(NP1 / 256, NB, NCHUNK), 256, 0, stream>>>(xyz1, xyz2, cand);
  knn_merge_kernel<<<dim3(MT / 256), 256, 0, stream>>>(cand, kidx, kw);
  interp_kernel<<<dim3(MT / 4), 256, 0, stream>>>(feat2, kidx, kw, fint);
  cast_both_kernel<<<dim3((H0 * KC / 8 + H1 * H0 / 8) / 256), 256, 0, stream>>>(W0, W1, w0b, w1b);
  gemm0_mfma_kernel<<<dim3(H0 / 128, GM), 256, 0, stream>>>(feat1, fint, w0b, b0, y0b, part0);
  bnfin_kernel<<<dim3(H0), 256, 0, stream>>>(part0, g0, be0, sc0, sh0);
  gemm1_mfma_kernel<<<dim3(1, GM), 256, 0, stream>>>(y0b, sc0, sh0, w1b, b1, y1, part1);
  bnfin_kernel<<<dim3(H1), 256, 0, stream>>>(part1, g1, be1, sc1, sh1);
  bnrelu_out_kernel<<<dim3(MT * H1 / 8 / 256), 256, 0, stream>>>(y1, sc1, sh1, out);
}